// Round 9
// baseline (609.661 us; speedup 1.0000x reference)
//
#include <hip/hip_runtime.h>
#include <hip/hip_bf16.h>
#include <hip/hip_fp16.h>
#include <math.h>

#define MAXH 3
#define NSB 9              // 512 nodes per bin
#define NS (1 << NSB)
#define SRCBITS 17         // n < 131072
#define SRCMASK ((1 << SRCBITS) - 1)
#define LOG2E 1.4426950408889634f
typedef unsigned int u32;
typedef unsigned char u8;

__device__ __forceinline__ float lrelu2(float x) { return fmaxf(x, 0.2f * x); }
__device__ __forceinline__ float fexp2(float x) {
#if __has_builtin(__builtin_amdgcn_exp2f)
    return __builtin_amdgcn_exp2f(x);
#else
    return exp2f(x);
#endif
}

// ---------------- BFS hierarchy (bitset reached, CSR in-neighbor scan) ----------------
__global__ void k_bfs_init(const int* __restrict__ seed_mask, int* dist, int n) {
    int i = blockIdx.x * blockDim.x + threadIdx.x;
    if (i < n) dist[i] = (seed_mask[i] == 0) ? 0 : (MAXH + 1);
}
__global__ void k_rbits_init(const int* __restrict__ seed_mask, u32* rbits, int nw, int n) {
    int w = blockIdx.x * blockDim.x + threadIdx.x;
    if (w < nw) {
        u32 b = 0;
        int base = w * 32;
        int lim = min(32, n - base);
        for (int j = 0; j < lim; j++)
            if (seed_mask[base + j] == 0) b |= (1u << j);
        rbits[w] = b;
    }
}
__global__ void k_bfs_scan(const int* __restrict__ rowptr, const int* __restrict__ csr_src,
                           const u32* __restrict__ rbits, u8* __restrict__ nbr, int n) {
    int i = blockIdx.x * blockDim.x + threadIdx.x;
    if (i < n) {
        if (!((rbits[i >> 5] >> (i & 31)) & 1u)) {
            int beg = rowptr[i], end = rowptr[i + 1];
            u8 f = 0;
            for (int k = beg; k < end; k++) {
                int s = csr_src[k];
                if ((rbits[s >> 5] >> (s & 31)) & 1u) { f = 1; break; }
            }
            nbr[i] = f;
        }
    }
}
__global__ void k_bfs_node(u32* rbits, int* dist, const u8* __restrict__ nbr, int h, int n) {
    int i = blockIdx.x * blockDim.x + threadIdx.x;
    if (i < n) {
        if (nbr[i] && !((rbits[i >> 5] >> (i & 31)) & 1u)) {
            dist[i] = h;
            atomicOr(&rbits[i >> 5], 1u << (i & 31));
        }
    }
}

// ---------------- CSR build: locality-binned 2-level counting sort ----------------
__global__ void k_bincount(const int4* __restrict__ dst4, int* bincnt, int E4) {
    __shared__ int cnt[256];
    int t = threadIdx.x;
    cnt[t] = 0;
    __syncthreads();
    int i = blockIdx.x * 256 + t;
    if (i < E4) {
        int4 d = dst4[i];
        atomicAdd(&cnt[d.x >> NSB], 1);
        atomicAdd(&cnt[d.y >> NSB], 1);
        atomicAdd(&cnt[d.z >> NSB], 1);
        atomicAdd(&cnt[d.w >> NSB], 1);
    }
    __syncthreads();
    if (cnt[t] > 0) atomicAdd(&bincnt[t], cnt[t]);
}

__global__ void k_binscan(const int* __restrict__ bincnt, int* binbase, int* bincur,
                          int* rowptr, int BINS, int E, int n) {
    __shared__ int sd[256];
    int t = threadIdx.x;
    int v = (t < BINS) ? bincnt[t] : 0;
    sd[t] = v;
    __syncthreads();
    for (int off = 1; off < 256; off <<= 1) {
        int add = (t >= off) ? sd[t - off] : 0;
        __syncthreads();
        sd[t] += add;
        __syncthreads();
    }
    int excl = sd[t] - v;
    if (t < BINS) { binbase[t] = excl; bincur[t] = excl; }
    if (t == 0) { binbase[BINS] = E; rowptr[n] = E; }
}

__global__ void k_binscatter(const int4* __restrict__ src4, const int4* __restrict__ dst4,
                             int* bincur, int* __restrict__ pairs, int E4, int BINS) {
    __shared__ int cnt[256], base[256];
    int t = threadIdx.x;
    cnt[t] = 0;
    __syncthreads();
    int i = blockIdx.x * 256 + t;
    int bin[4], rank[4], pack[4];
    bool valid = i < E4;
    if (valid) {
        int4 s = src4[i], d = dst4[i];
        bin[0] = d.x >> NSB; pack[0] = ((d.x & (NS - 1)) << SRCBITS) | s.x;
        bin[1] = d.y >> NSB; pack[1] = ((d.y & (NS - 1)) << SRCBITS) | s.y;
        bin[2] = d.z >> NSB; pack[2] = ((d.z & (NS - 1)) << SRCBITS) | s.z;
        bin[3] = d.w >> NSB; pack[3] = ((d.w & (NS - 1)) << SRCBITS) | s.w;
        rank[0] = atomicAdd(&cnt[bin[0]], 1);
        rank[1] = atomicAdd(&cnt[bin[1]], 1);
        rank[2] = atomicAdd(&cnt[bin[2]], 1);
        rank[3] = atomicAdd(&cnt[bin[3]], 1);
    }
    __syncthreads();
    if (t < BINS && cnt[t] > 0) base[t] = atomicAdd(&bincur[t], cnt[t]);
    __syncthreads();
    if (valid) {
        pairs[base[bin[0]] + rank[0]] = pack[0];
        pairs[base[bin[1]] + rank[1]] = pack[1];
        pairs[base[bin[2]] + rank[2]] = pack[2];
        pairs[base[bin[3]] + rank[3]] = pack[3];
    }
}

__global__ void k_binsort(const int* __restrict__ pairs, const int* __restrict__ binbase,
                          int* __restrict__ rowptr, int* __restrict__ csr_src, int n) {
    __shared__ int hist[NS];
    const int b = blockIdx.x, t = threadIdx.x;
    const int nbeg = b << NSB;
    const int ebeg = binbase[b];
    const int ecnt = binbase[b + 1] - ebeg;
    hist[t] = 0; hist[t + 256] = 0;
    __syncthreads();
    for (int i = t; i < ecnt; i += 256)
        atomicAdd(&hist[(u32)pairs[ebeg + i] >> SRCBITS], 1);
    for (int d = 1; d < NS; d <<= 1) {
        __syncthreads();
        int idx = (t + 1) * (d << 1) - 1;
        if (idx < NS) hist[idx] += hist[idx - d];
    }
    __syncthreads();
    if (t == 0) hist[NS - 1] = 0;
    for (int d = NS / 2; d >= 1; d >>= 1) {
        __syncthreads();
        int idx = (t + 1) * (d << 1) - 1;
        if (idx < NS) { int tmp = hist[idx - d]; hist[idx - d] = hist[idx]; hist[idx] += tmp; }
    }
    __syncthreads();
    int g0 = nbeg + t, g1 = nbeg + t + 256;
    if (g0 < n) rowptr[g0] = ebeg + hist[t];
    if (g1 < n) rowptr[g1] = ebeg + hist[t + 256];
    __syncthreads();
    for (int i = t; i < ecnt; i += 256) {
        int p = pairs[ebeg + i];
        int pos = atomicAdd(&hist[(u32)p >> SRCBITS], 1);
        csr_src[ebeg + pos] = p & SRCMASK;
    }
}

// ---------------- register-tiled GEMM, fp16 out, fused attention logits ----------------
template <typename AT, int K, int KW, int MP, int MREAL, bool AUG, int AH, int AC, int THREADS>
__launch_bounds__(THREADS)
__global__ void k_gemm_t(const AT* __restrict__ A, const float* __restrict__ W,
                         const float* __restrict__ a_s, const float* __restrict__ a_d,
                         const int* __restrict__ dist, __half* __restrict__ out,
                         float* __restrict__ als, float* __restrict__ ald, int n) {
    constexpr int COLT = MP / 4;
    constexpr int ROWT = THREADS / COLT;
    constexpr int RPT = 64 / ROWT;  // = 4
    constexpr int BK = 64;
    constexpr int SAP = BK + 4;
    __shared__ float sA[64 * SAP];
    __shared__ float sW[KW * MP];

    for (int i = threadIdx.x; i < KW * MP; i += THREADS) {
        int r = i / MP, c = i % MP;
        sW[i] = (c < MREAL) ? W[r * MREAL + c] : 0.0f;
    }
    const int tcol = threadIdx.x % COLT;
    const int trow = threadIdx.x / COLT;
    const int rowbase = blockIdx.x * 64;

    float4 acc[RPT];
#pragma unroll
    for (int r = 0; r < RPT; r++) acc[r] = float4{0.f, 0.f, 0.f, 0.f};

    for (int k0 = 0; k0 < K; k0 += BK) {
        __syncthreads();
        if constexpr (sizeof(AT) == 4) {
            for (int i = threadIdx.x; i < 64 * (BK / 4); i += THREADS) {
                int r = i / (BK / 4), c4 = i % (BK / 4);
                int row = rowbase + r;
                float4 v = float4{0.f, 0.f, 0.f, 0.f};
                if (row < n) v = *(const float4*)&A[(size_t)row * K + k0 + c4 * 4];
                *(float4*)&sA[r * SAP + c4 * 4] = v;
            }
        } else {
            for (int i = threadIdx.x; i < 64 * (BK / 8); i += THREADS) {
                int r = i / (BK / 8), c8 = i % (BK / 8);
                int row = rowbase + r;
                float f[8];
#pragma unroll
                for (int j = 0; j < 8; j++) f[j] = 0.0f;
                if (row < n) {
                    int4 raw = *(const int4*)&A[(size_t)row * K + k0 + c8 * 8];
                    float2 p0 = __half22float2(*(const __half2*)&raw.x);
                    float2 p1 = __half22float2(*(const __half2*)&raw.y);
                    float2 p2 = __half22float2(*(const __half2*)&raw.z);
                    float2 p3 = __half22float2(*(const __half2*)&raw.w);
                    f[0] = p0.x; f[1] = p0.y; f[2] = p1.x; f[3] = p1.y;
                    f[4] = p2.x; f[5] = p2.y; f[6] = p3.x; f[7] = p3.y;
                }
#pragma unroll
                for (int j = 0; j < 8; j++) sA[r * SAP + c8 * 8 + j] = f[j];
            }
        }
        __syncthreads();
#pragma unroll 2
        for (int k4 = 0; k4 < BK / 4; k4++) {
            float4 w0 = *(const float4*)&sW[(k0 + k4 * 4 + 0) * MP + tcol * 4];
            float4 w1 = *(const float4*)&sW[(k0 + k4 * 4 + 1) * MP + tcol * 4];
            float4 w2 = *(const float4*)&sW[(k0 + k4 * 4 + 2) * MP + tcol * 4];
            float4 w3 = *(const float4*)&sW[(k0 + k4 * 4 + 3) * MP + tcol * 4];
#pragma unroll
            for (int r = 0; r < RPT; r++) {
                float4 a = *(const float4*)&sA[(trow * RPT + r) * SAP + k4 * 4];
                acc[r].x += a.x * w0.x + a.y * w1.x + a.z * w2.x + a.w * w3.x;
                acc[r].y += a.x * w0.y + a.y * w1.y + a.z * w2.y + a.w * w3.y;
                acc[r].z += a.x * w0.z + a.y * w1.z + a.z * w2.z + a.w * w3.z;
                acc[r].w += a.x * w0.w + a.y * w1.w + a.z * w2.w + a.w * w3.w;
            }
        }
    }

    float as_[4], ad_[4];
#pragma unroll
    for (int j = 0; j < 4; j++) {
        int col = tcol * 4 + j;
        bool ok = col < MREAL;
        as_[j] = ok ? a_s[col] * LOG2E : 0.0f;
        ad_[j] = ok ? a_d[col] * LOG2E : 0.0f;
    }
    constexpr int TPH = AC / 4;
    constexpr int RW = (TPH & (TPH - 1)) ? 16 : TPH;
    const int head = (tcol * 4) / AC;

#pragma unroll
    for (int r = 0; r < RPT; r++) {
        int row = rowbase + trow * RPT + r;
        if (AUG && row < n) {
            int d = dist[row];
            if (d <= MAXH) {
                float4 wd = *(const float4*)&sW[(K + d) * MP + tcol * 4];
                acc[r].x += wd.x; acc[r].y += wd.y; acc[r].z += wd.z; acc[r].w += wd.w;
            }
        }
        float ps = acc[r].x * as_[0] + acc[r].y * as_[1] + acc[r].z * as_[2] + acc[r].w * as_[3];
        float pd = acc[r].x * ad_[0] + acc[r].y * ad_[1] + acc[r].z * ad_[2] + acc[r].w * ad_[3];
#pragma unroll
        for (int o = 1; o < RW; o <<= 1) {
            ps += __shfl_xor(ps, o);
            pd += __shfl_xor(pd, o);
        }
        if (row < n) {
            if ((tcol % RW) == 0) {
                als[(size_t)row * AH + head] = ps;
                ald[(size_t)row * AH + head] = pd;
            }
            if (tcol * 4 + 3 < MREAL) {
                __half2* op = (__half2*)&out[(size_t)row * MREAL + tcol * 4];
                op[0] = __floats2half2_rn(acc[r].x, acc[r].y);
                op[1] = __floats2half2_rn(acc[r].z, acc[r].w);
            }
        }
    }
}

// ---------------- fused GAT: batched-exp pre-pass + gather channel pass ----------------
// Pre-pass lane layout: lane = es*H + ph  (ES=64/H edge-slots x H heads): ONE v_exp
// instruction computes p for ES edges. p kept in statically-indexed VGPRs p[H].
// Channel pass: alpha via ds_bpermute, h-row via scalar (readlane) addressing.
// Softmax normalized by self-logit m0 (no max pass); self edge folded into init.
// MODE: 1=ELU (OT=half), 2=gate (OT=half), 3=log_softmax (OT=float)
template <int H, int C, int CH, int MODE, typename OT>
__launch_bounds__(256)
__global__ void k_gat(const int* __restrict__ rowptr, const int* __restrict__ csr_src,
                      const __half* __restrict__ h, const float* __restrict__ als,
                      const float* __restrict__ ald, const float* __restrict__ bias,
                      const int* __restrict__ dist, const float* __restrict__ Wg,
                      const float* __restrict__ bg, OT* __restrict__ out, int n) {
    constexpr int TOT = H * C;
    constexpr int NL = TOT / CH;
    constexpr int ES = 64 / H;
    const int lane = threadIdx.x & 63;
    const int node = blockIdx.x * 4 + (threadIdx.x >> 6);
    if (node >= n) return;
    const int beg = rowptr[node];
    const int deg = rowptr[node + 1] - beg;

    // pre-pass mapping
    const int ph = lane & (H - 1);
    const int es = lane / H;
    const float ald_ph = ald[(size_t)node * H + ph];
    const float m0_ph = lrelu2(als[(size_t)node * H + ph] + ald_ph);

    // channel-pass mapping
    const int cl = (lane < NL) ? lane : 0;
    const int hd = (cl * CH) / C;

    float s = 0.0f;
    float ax, ay = 0.0f;
    if (CH == 2) {
        float2 hv = __half22float2(*(const __half2*)(h + (size_t)node * TOT + cl * 2));
        ax = hv.x; ay = hv.y;
    } else {
        ax = __half2float(h[(size_t)node * TOT + cl]);
    }

    for (int base = 0; base < deg; base += 64) {
        const int myE = base + lane;
        int sReg = (myE < deg) ? csr_src[beg + myE] : 0;
        const int cnt = min(64, deg - base);
        float p[H];
        // ---- pre-pass: ES edges per v_exp ----
#pragma unroll
        for (int sp = 0; sp < H; sp++) {
            if (sp * ES >= cnt) break;
            int eIdx = sp * ES + es;
            int sN = (H == 1) ? sReg : __shfl(sReg, eIdx);
            float t = als[(size_t)sN * H + ph] + ald_ph;
            float pv = fexp2(lrelu2(t) - m0_ph);
            pv = (eIdx < cnt) ? pv : 0.0f;
            p[sp] = pv;
            s += pv;
        }
        // ---- channel pass ----
#pragma unroll
        for (int sp = 0; sp < H; sp++) {
            if (sp * ES >= cnt) break;
            float psp = p[sp];
            int lim = min(ES, cnt - sp * ES);
            for (int j = 0; j < lim; j++) {
                float alpha = __shfl(psp, j * H + hd);
                int sN = __builtin_amdgcn_readlane(sReg, sp * ES + j);
                if (CH == 2) {
                    float2 hf = __half22float2(*(const __half2*)(h + (size_t)sN * TOT + cl * 2));
                    ax += alpha * hf.x;
                    ay += alpha * hf.y;
                } else {
                    ax += alpha * __half2float(h[(size_t)sN * TOT + cl]);
                }
            }
        }
    }

    // reduce s over edge-slot groups (same ph), add self weight (1.0)
#pragma unroll
    for (int off = H; off < 64; off <<= 1) s += __shfl_xor(s, off);
    float inv_ph = 1.0f / (s + 1.0f + 1e-16f);
    float inv = __shfl(inv_ph, hd);  // lane 'hd' has ph==hd

    float vx = ax * inv + bias[cl * CH];
    float vy = (CH == 2) ? (ay * inv + bias[cl * CH + 1]) : 0.0f;

    if (MODE == 1) {  // ELU -> fp16
        vx = vx > 0.0f ? vx : expm1f(vx);
        ((__half*)out)[(size_t)node * TOT + cl] = __float2half(vx);
    } else if (MODE == 2) {  // gate -> fp16
        float2 wg = *(const float2*)&Wg[cl * 2];
        float part = vx * wg.x + vy * wg.y;
#pragma unroll
        for (int off = 32; off > 0; off >>= 1) part += __shfl_xor(part, off);
        int d = dist[node];
        float hop = (d <= MAXH) ? (float)d : 0.0f;
        float g = 1.0f / (1.0f + __expf(-(part + hop * Wg[128] + bg[0])));
        *(__half2*)&((__half*)out)[(size_t)node * TOT + cl * 2] =
            __floats2half2_rn(vx * g, vy * g);
    } else if (MODE == 3) {  // log_softmax -> fp32
        float v = (lane < NL) ? vx : -INFINITY;
        float mm = v;
#pragma unroll
        for (int off = 32; off > 0; off >>= 1) mm = fmaxf(mm, __shfl_xor(mm, off));
        float ex = (lane < NL) ? __expf(v - mm) : 0.0f;
        float ss = ex;
#pragma unroll
        for (int off = 32; off > 0; off >>= 1) ss += __shfl_xor(ss, off);
        float ls = logf(ss);
        if (lane < NL) ((float*)out)[(size_t)node * TOT + cl] = v - mm - ls;
    }
}

static inline int nblk(long long t, int b) { return (int)((t + b - 1) / b); }

extern "C" void kernel_launch(void* const* d_in, const int* in_sizes, int n_in,
                              void* d_out, int out_size, void* d_ws, size_t ws_size,
                              hipStream_t stream) {
    const float* x = (const float*)d_in[0];
    const int* eidx = (const int*)d_in[1];
    const int* seed_mask = (const int*)d_in[2];
    const float* W1 = (const float*)d_in[3];
    const float* a1s = (const float*)d_in[4];
    const float* a1d = (const float*)d_in[5];
    const float* b1 = (const float*)d_in[6];
    const float* W2 = (const float*)d_in[7];
    const float* a2s = (const float*)d_in[8];
    const float* a2d = (const float*)d_in[9];
    const float* b2 = (const float*)d_in[10];
    const float* W3 = (const float*)d_in[11];
    const float* a3s = (const float*)d_in[12];
    const float* a3d = (const float*)d_in[13];
    const float* b3 = (const float*)d_in[14];
    const float* Wg = (const float*)d_in[15];
    const float* bg = (const float*)d_in[16];

    const int n = in_sizes[0] / 128;        // 100000
    const long long E = in_sizes[1] / 2;    // 1600000
    const int E4 = (int)(E / 4);
    const int4* src4 = (const int4*)eidx;
    const int4* dst4 = (const int4*)(eidx + E);
    const int BINS = (n + NS - 1) >> NSB;   // 196 <= 256
    const int NW = (n + 31) / 32;

    char* ws = (char*)d_ws;
    size_t off = 0;
    auto alloc = [&](size_t bytes) -> void* {
        void* p = ws + off;
        off = (off + bytes + 255) & ~(size_t)255;
        return p;
    };
    int* dist    = (int*)alloc((size_t)n * 4);
    u32* rbits   = (u32*)alloc((size_t)NW * 4);
    u8* nbr      = (u8*)alloc((size_t)n);
    int* rowptr  = (int*)alloc((size_t)(n + 1) * 4);
    int* bincnt  = (int*)alloc(256 * 4);
    int* binbase = (int*)alloc(257 * 4);
    int* bincur  = (int*)alloc(256 * 4);
    int* csr_src = (int*)alloc((size_t)E * 4);
    float* als   = (float*)alloc((size_t)n * 8 * 4);
    float* ald   = (float*)alloc((size_t)n * 8 * 4);
    __half* hbuf = (__half*)alloc((size_t)n * 128 * 2);  // GEMM out (h)
    __half* abuf = (__half*)alloc((size_t)n * 128 * 2);  // GAT out (next A)
    int* pairs   = (int*)abuf;  // alias: pairs only live during CSR build
    float* out = (float*)d_out;

    const int BS = 256;

    // ---- CSR build: binned counting sort ----
    hipMemsetAsync(bincnt, 0, 256 * 4, stream);
    k_bfs_init<<<nblk(n, BS), BS, 0, stream>>>(seed_mask, dist, n);
    k_rbits_init<<<nblk(NW, BS), BS, 0, stream>>>(seed_mask, rbits, NW, n);
    k_bincount<<<nblk(E4, BS), BS, 0, stream>>>(dst4, bincnt, E4);
    k_binscan<<<1, 256, 0, stream>>>(bincnt, binbase, bincur, rowptr, BINS, (int)E, n);
    k_binscatter<<<nblk(E4, BS), BS, 0, stream>>>(src4, dst4, bincur, pairs, E4, BINS);
    k_binsort<<<BINS, 256, 0, stream>>>(pairs, binbase, rowptr, csr_src, n);

    // ---- BFS hierarchy via CSR (bitset reached) ----
    for (int h = 1; h <= MAXH; h++) {
        k_bfs_scan<<<nblk(n, BS), BS, 0, stream>>>(rowptr, csr_src, rbits, nbr, n);
        k_bfs_node<<<nblk(n, BS), BS, 0, stream>>>(rbits, dist, nbr, h, n);
    }

    // ---- Layer 1: aug(132) -> 8x8, ELU fused ----
    k_gemm_t<float, 128, 132, 64, 64, true, 8, 8, 256>
        <<<nblk(n, 64), 256, 0, stream>>>(x, W1, a1s, a1d, dist, hbuf, als, ald, n);
    k_gat<8, 8, 1, 1, __half><<<nblk(n, 4), 256, 0, stream>>>(
        rowptr, csr_src, hbuf, als, ald, b1, nullptr, nullptr, nullptr, abuf, n);

    // ---- Layer 2: 64 -> 8x16, gate fused ----
    k_gemm_t<__half, 64, 64, 128, 128, false, 8, 16, 512>
        <<<nblk(n, 64), 512, 0, stream>>>(abuf, W2, a2s, a2d, nullptr, hbuf, als, ald, n);
    k_gat<8, 16, 2, 2, __half><<<nblk(n, 4), 256, 0, stream>>>(
        rowptr, csr_src, hbuf, als, ald, b2, dist, Wg, bg, abuf, n);

    // ---- Layer 3: 128 -> 1x40, log_softmax fused ----
    k_gemm_t<__half, 128, 128, 64, 40, false, 1, 40, 256>
        <<<nblk(n, 64), 256, 0, stream>>>(abuf, W3, a3s, a3d, nullptr, hbuf, als, ald, n);
    k_gat<1, 40, 1, 3, float><<<nblk(n, 4), 256, 0, stream>>>(
        rowptr, csr_src, hbuf, als, ald, b3, nullptr, nullptr, nullptr, out, n);
}

// Round 10
// 567.039 us; speedup vs baseline: 1.0752x; 1.0752x over previous
//
#include <hip/hip_runtime.h>
#include <hip/hip_bf16.h>
#include <hip/hip_fp16.h>
#include <math.h>

#define MAXH 3
#define NSB 9              // 512 nodes per bin
#define NS (1 << NSB)
#define SRCBITS 17         // n < 131072
#define SRCMASK ((1 << SRCBITS) - 1)
#define LOG2E 1.4426950408889634f
typedef unsigned int u32;
typedef unsigned char u8;

__device__ __forceinline__ float lrelu2(float x) { return fmaxf(x, 0.2f * x); }
__device__ __forceinline__ float fexp2(float x) {
#if __has_builtin(__builtin_amdgcn_exp2f)
    return __builtin_amdgcn_exp2f(x);
#else
    return exp2f(x);
#endif
}

// ---------------- BFS hierarchy (bitset reached, CSR in-neighbor scan) ----------------
__global__ void k_bfs_init(const int* __restrict__ seed_mask, int* dist, int n) {
    int i = blockIdx.x * blockDim.x + threadIdx.x;
    if (i < n) dist[i] = (seed_mask[i] == 0) ? 0 : (MAXH + 1);
}
__global__ void k_rbits_init(const int* __restrict__ seed_mask, u32* rbits, int nw, int n) {
    int w = blockIdx.x * blockDim.x + threadIdx.x;
    if (w < nw) {
        u32 b = 0;
        int base = w * 32;
        int lim = min(32, n - base);
        for (int j = 0; j < lim; j++)
            if (seed_mask[base + j] == 0) b |= (1u << j);
        rbits[w] = b;
    }
}
__global__ void k_bfs_scan(const int* __restrict__ rowptr, const int* __restrict__ csr_src,
                           const u32* __restrict__ rbits, u8* __restrict__ nbr, int n) {
    int i = blockIdx.x * blockDim.x + threadIdx.x;
    if (i < n) {
        if (!((rbits[i >> 5] >> (i & 31)) & 1u)) {
            int beg = rowptr[i], end = rowptr[i + 1];
            u8 f = 0;
            for (int k = beg; k < end; k++) {
                int s = csr_src[k];
                if ((rbits[s >> 5] >> (s & 31)) & 1u) { f = 1; break; }
            }
            nbr[i] = f;
        }
    }
}
__global__ void k_bfs_node(u32* rbits, int* dist, const u8* __restrict__ nbr, int h, int n) {
    int i = blockIdx.x * blockDim.x + threadIdx.x;
    if (i < n) {
        if (nbr[i] && !((rbits[i >> 5] >> (i & 31)) & 1u)) {
            dist[i] = h;
            atomicOr(&rbits[i >> 5], 1u << (i & 31));
        }
    }
}

// ---------------- CSR build: locality-binned 2-level counting sort ----------------
__global__ void k_bincount(const int4* __restrict__ dst4, int* bincnt, int E4) {
    __shared__ int cnt[256];
    int t = threadIdx.x;
    cnt[t] = 0;
    __syncthreads();
    int i = blockIdx.x * 256 + t;
    if (i < E4) {
        int4 d = dst4[i];
        atomicAdd(&cnt[d.x >> NSB], 1);
        atomicAdd(&cnt[d.y >> NSB], 1);
        atomicAdd(&cnt[d.z >> NSB], 1);
        atomicAdd(&cnt[d.w >> NSB], 1);
    }
    __syncthreads();
    if (cnt[t] > 0) atomicAdd(&bincnt[t], cnt[t]);
}

__global__ void k_binscan(const int* __restrict__ bincnt, int* binbase, int* bincur,
                          int* rowptr, int BINS, int E, int n) {
    __shared__ int sd[256];
    int t = threadIdx.x;
    int v = (t < BINS) ? bincnt[t] : 0;
    sd[t] = v;
    __syncthreads();
    for (int off = 1; off < 256; off <<= 1) {
        int add = (t >= off) ? sd[t - off] : 0;
        __syncthreads();
        sd[t] += add;
        __syncthreads();
    }
    int excl = sd[t] - v;
    if (t < BINS) { binbase[t] = excl; bincur[t] = excl; }
    if (t == 0) { binbase[BINS] = E; rowptr[n] = E; }
}

__global__ void k_binscatter(const int4* __restrict__ src4, const int4* __restrict__ dst4,
                             int* bincur, int* __restrict__ pairs, int E4, int BINS) {
    __shared__ int cnt[256], base[256];
    int t = threadIdx.x;
    cnt[t] = 0;
    __syncthreads();
    int i = blockIdx.x * 256 + t;
    int bin[4], rank[4], pack[4];
    bool valid = i < E4;
    if (valid) {
        int4 s = src4[i], d = dst4[i];
        bin[0] = d.x >> NSB; pack[0] = ((d.x & (NS - 1)) << SRCBITS) | s.x;
        bin[1] = d.y >> NSB; pack[1] = ((d.y & (NS - 1)) << SRCBITS) | s.y;
        bin[2] = d.z >> NSB; pack[2] = ((d.z & (NS - 1)) << SRCBITS) | s.z;
        bin[3] = d.w >> NSB; pack[3] = ((d.w & (NS - 1)) << SRCBITS) | s.w;
        rank[0] = atomicAdd(&cnt[bin[0]], 1);
        rank[1] = atomicAdd(&cnt[bin[1]], 1);
        rank[2] = atomicAdd(&cnt[bin[2]], 1);
        rank[3] = atomicAdd(&cnt[bin[3]], 1);
    }
    __syncthreads();
    if (t < BINS && cnt[t] > 0) base[t] = atomicAdd(&bincur[t], cnt[t]);
    __syncthreads();
    if (valid) {
        pairs[base[bin[0]] + rank[0]] = pack[0];
        pairs[base[bin[1]] + rank[1]] = pack[1];
        pairs[base[bin[2]] + rank[2]] = pack[2];
        pairs[base[bin[3]] + rank[3]] = pack[3];
    }
}

__global__ void k_binsort(const int* __restrict__ pairs, const int* __restrict__ binbase,
                          int* __restrict__ rowptr, int* __restrict__ csr_src, int n) {
    __shared__ int hist[NS];
    const int b = blockIdx.x, t = threadIdx.x;
    const int nbeg = b << NSB;
    const int ebeg = binbase[b];
    const int ecnt = binbase[b + 1] - ebeg;
    hist[t] = 0; hist[t + 256] = 0;
    __syncthreads();
    for (int i = t; i < ecnt; i += 256)
        atomicAdd(&hist[(u32)pairs[ebeg + i] >> SRCBITS], 1);
    for (int d = 1; d < NS; d <<= 1) {
        __syncthreads();
        int idx = (t + 1) * (d << 1) - 1;
        if (idx < NS) hist[idx] += hist[idx - d];
    }
    __syncthreads();
    if (t == 0) hist[NS - 1] = 0;
    for (int d = NS / 2; d >= 1; d >>= 1) {
        __syncthreads();
        int idx = (t + 1) * (d << 1) - 1;
        if (idx < NS) { int tmp = hist[idx - d]; hist[idx - d] = hist[idx]; hist[idx] += tmp; }
    }
    __syncthreads();
    int g0 = nbeg + t, g1 = nbeg + t + 256;
    if (g0 < n) rowptr[g0] = ebeg + hist[t];
    if (g1 < n) rowptr[g1] = ebeg + hist[t + 256];
    __syncthreads();
    for (int i = t; i < ecnt; i += 256) {
        int p = pairs[ebeg + i];
        int pos = atomicAdd(&hist[(u32)p >> SRCBITS], 1);
        csr_src[ebeg + pos] = p & SRCMASK;
    }
}

// ---------------- register-tiled GEMM, fp16 out, fused attention logits ----------------
template <typename AT, int K, int KW, int MP, int MREAL, bool AUG, int AH, int AC, int THREADS>
__launch_bounds__(THREADS)
__global__ void k_gemm_t(const AT* __restrict__ A, const float* __restrict__ W,
                         const float* __restrict__ a_s, const float* __restrict__ a_d,
                         const int* __restrict__ dist, __half* __restrict__ out,
                         float* __restrict__ als, float* __restrict__ ald, int n) {
    constexpr int COLT = MP / 4;
    constexpr int ROWT = THREADS / COLT;
    constexpr int RPT = 64 / ROWT;  // = 4
    constexpr int BK = 64;
    constexpr int SAP = BK + 4;
    __shared__ float sA[64 * SAP];
    __shared__ float sW[KW * MP];

    for (int i = threadIdx.x; i < KW * MP; i += THREADS) {
        int r = i / MP, c = i % MP;
        sW[i] = (c < MREAL) ? W[r * MREAL + c] : 0.0f;
    }
    const int tcol = threadIdx.x % COLT;
    const int trow = threadIdx.x / COLT;
    const int rowbase = blockIdx.x * 64;

    float4 acc[RPT];
#pragma unroll
    for (int r = 0; r < RPT; r++) acc[r] = float4{0.f, 0.f, 0.f, 0.f};

    for (int k0 = 0; k0 < K; k0 += BK) {
        __syncthreads();
        if constexpr (sizeof(AT) == 4) {
            for (int i = threadIdx.x; i < 64 * (BK / 4); i += THREADS) {
                int r = i / (BK / 4), c4 = i % (BK / 4);
                int row = rowbase + r;
                float4 v = float4{0.f, 0.f, 0.f, 0.f};
                if (row < n) v = *(const float4*)&A[(size_t)row * K + k0 + c4 * 4];
                *(float4*)&sA[r * SAP + c4 * 4] = v;
            }
        } else {
            for (int i = threadIdx.x; i < 64 * (BK / 8); i += THREADS) {
                int r = i / (BK / 8), c8 = i % (BK / 8);
                int row = rowbase + r;
                float f[8];
#pragma unroll
                for (int j = 0; j < 8; j++) f[j] = 0.0f;
                if (row < n) {
                    int4 raw = *(const int4*)&A[(size_t)row * K + k0 + c8 * 8];
                    float2 p0 = __half22float2(*(const __half2*)&raw.x);
                    float2 p1 = __half22float2(*(const __half2*)&raw.y);
                    float2 p2 = __half22float2(*(const __half2*)&raw.z);
                    float2 p3 = __half22float2(*(const __half2*)&raw.w);
                    f[0] = p0.x; f[1] = p0.y; f[2] = p1.x; f[3] = p1.y;
                    f[4] = p2.x; f[5] = p2.y; f[6] = p3.x; f[7] = p3.y;
                }
#pragma unroll
                for (int j = 0; j < 8; j++) sA[r * SAP + c8 * 8 + j] = f[j];
            }
        }
        __syncthreads();
#pragma unroll 2
        for (int k4 = 0; k4 < BK / 4; k4++) {
            float4 w0 = *(const float4*)&sW[(k0 + k4 * 4 + 0) * MP + tcol * 4];
            float4 w1 = *(const float4*)&sW[(k0 + k4 * 4 + 1) * MP + tcol * 4];
            float4 w2 = *(const float4*)&sW[(k0 + k4 * 4 + 2) * MP + tcol * 4];
            float4 w3 = *(const float4*)&sW[(k0 + k4 * 4 + 3) * MP + tcol * 4];
#pragma unroll
            for (int r = 0; r < RPT; r++) {
                float4 a = *(const float4*)&sA[(trow * RPT + r) * SAP + k4 * 4];
                acc[r].x += a.x * w0.x + a.y * w1.x + a.z * w2.x + a.w * w3.x;
                acc[r].y += a.x * w0.y + a.y * w1.y + a.z * w2.y + a.w * w3.y;
                acc[r].z += a.x * w0.z + a.y * w1.z + a.z * w2.z + a.w * w3.z;
                acc[r].w += a.x * w0.w + a.y * w1.w + a.z * w2.w + a.w * w3.w;
            }
        }
    }

    float as_[4], ad_[4];
#pragma unroll
    for (int j = 0; j < 4; j++) {
        int col = tcol * 4 + j;
        bool ok = col < MREAL;
        as_[j] = ok ? a_s[col] * LOG2E : 0.0f;
        ad_[j] = ok ? a_d[col] * LOG2E : 0.0f;
    }
    constexpr int TPH = AC / 4;
    constexpr int RW = (TPH & (TPH - 1)) ? 16 : TPH;
    const int head = (tcol * 4) / AC;

#pragma unroll
    for (int r = 0; r < RPT; r++) {
        int row = rowbase + trow * RPT + r;
        if (AUG && row < n) {
            int d = dist[row];
            if (d <= MAXH) {
                float4 wd = *(const float4*)&sW[(K + d) * MP + tcol * 4];
                acc[r].x += wd.x; acc[r].y += wd.y; acc[r].z += wd.z; acc[r].w += wd.w;
            }
        }
        float ps = acc[r].x * as_[0] + acc[r].y * as_[1] + acc[r].z * as_[2] + acc[r].w * as_[3];
        float pd = acc[r].x * ad_[0] + acc[r].y * ad_[1] + acc[r].z * ad_[2] + acc[r].w * ad_[3];
#pragma unroll
        for (int o = 1; o < RW; o <<= 1) {
            ps += __shfl_xor(ps, o);
            pd += __shfl_xor(pd, o);
        }
        if (row < n) {
            if ((tcol % RW) == 0) {
                als[(size_t)row * AH + head] = ps;
                ald[(size_t)row * AH + head] = pd;
            }
            if (tcol * 4 + 3 < MREAL) {
                __half2* op = (__half2*)&out[(size_t)row * MREAL + tcol * 4];
                op[0] = __floats2half2_rn(acc[r].x, acc[r].y);
                op[1] = __floats2half2_rn(acc[r].z, acc[r].w);
            }
        }
    }
}

// ---------------- fused GAT (round-8 form): single-pass no-max softmax, readlane ----
// MODE: 2=gate (OT=half). Used for the TOT=128 layer (all lanes carry channels).
template <int H, int C, int CH, int MODE, typename OT>
__launch_bounds__(256)
__global__ void k_gat(const int* __restrict__ rowptr, const int* __restrict__ csr_src,
                      const __half* __restrict__ h, const float* __restrict__ als,
                      const float* __restrict__ ald, const float* __restrict__ bias,
                      const int* __restrict__ dist, const float* __restrict__ Wg,
                      const float* __restrict__ bg, OT* __restrict__ out, int n) {
    constexpr int TOT = H * C;
    constexpr int NL = TOT / CH;
    const int lane = threadIdx.x & 63;
    const int node = blockIdx.x * 4 + (threadIdx.x >> 6);
    if (node >= n) return;
    const int beg = rowptr[node];
    const int deg = rowptr[node + 1] - beg;

    const int cl = (lane < NL) ? lane : 0;
    const int hd = (cl * CH) / C;
    const float ald_hd = ald[(size_t)node * H + hd];
    const float m0 = lrelu2(als[(size_t)node * H + hd] + ald_hd);

    float s = 1.0f, ax, ay = 0.0f;
    if (CH == 2) {
        float2 hv = __half22float2(*(const __half2*)(h + (size_t)node * TOT + cl * 2));
        ax = hv.x; ay = hv.y;
    } else {
        ax = __half2float(h[(size_t)node * TOT + cl]);
    }

    auto body = [&](int sN) {
        float t = als[(size_t)sN * H + hd] + ald_hd;
        float p = fexp2(lrelu2(t) - m0);
        s += p;
        if (CH == 2) {
            float2 hf = __half22float2(*(const __half2*)(h + (size_t)sN * TOT + cl * 2));
            ax += p * hf.x;
            ay += p * hf.y;
        } else {
            ax += p * __half2float(h[(size_t)sN * TOT + cl]);
        }
    };

    for (int base = 0; base < deg; base += 64) {
        const int myE = base + lane;
        int sReg = (myE < deg) ? csr_src[beg + myE] : 0;
        const int cnt = min(64, deg - base);
        int e = 0;
        for (; e + 4 <= cnt; e += 4) {
            body(__builtin_amdgcn_readlane(sReg, e));
            body(__builtin_amdgcn_readlane(sReg, e + 1));
            body(__builtin_amdgcn_readlane(sReg, e + 2));
            body(__builtin_amdgcn_readlane(sReg, e + 3));
        }
        for (; e < cnt; e++) body(__builtin_amdgcn_readlane(sReg, e));
    }

    const float inv = 1.0f / (s + 1e-16f);
    float vx = ax * inv + bias[cl * CH];
    float vy = (CH == 2) ? (ay * inv + bias[cl * CH + 1]) : 0.0f;

    if (MODE == 2) {  // gate -> fp16
        float2 wg = *(const float2*)&Wg[cl * 2];
        float part = vx * wg.x + vy * wg.y;
#pragma unroll
        for (int off = 32; off > 0; off >>= 1) part += __shfl_xor(part, off);
        int d = dist[node];
        float hop = (d <= MAXH) ? (float)d : 0.0f;
        float g = 1.0f / (1.0f + __expf(-(part + hop * Wg[128] + bg[0])));
        *(__half2*)&((__half*)out)[(size_t)node * TOT + cl * 2] =
            __floats2half2_rn(vx * g, vy * g);
    }
}

// ---------------- GAT layer 1 (H=8,C=8,TOT=64): 2 half-waves, interleaved edges ----
__launch_bounds__(256)
__global__ void k_gat1h(const int* __restrict__ rowptr, const int* __restrict__ csr_src,
                        const __half* __restrict__ h, const float* __restrict__ als,
                        const float* __restrict__ ald, const float* __restrict__ bias,
                        __half* __restrict__ out, int n) {
    const int lane = threadIdx.x & 63;
    const int node = blockIdx.x * 4 + (threadIdx.x >> 6);
    if (node >= n) return;
    const int beg = rowptr[node];
    const int deg = rowptr[node + 1] - beg;
    const int half_id = lane >> 5;
    const int l = lane & 31;          // channel pair (2l, 2l+1)
    const int ph = l >> 2;            // head of pair (C=8)
    const float ald_ph = ald[(size_t)node * 8 + ph];
    const float m0 = lrelu2(als[(size_t)node * 8 + ph] + ald_ph);

    float2 hv = __half22float2(*(const __half2*)(h + (size_t)node * 64 + 2 * l));
    float ax = half_id ? 0.0f : hv.x;
    float ay = half_id ? 0.0f : hv.y;
    float s  = half_id ? 0.0f : 1.0f;   // self weight = exp2(m0-m0) = 1

    for (int base = 0; base < deg; base += 64) {
        const int cnt = min(64, deg - base);
        const int iters = (cnt + 1) >> 1;
#pragma unroll 4
        for (int j = 0; j < iters; j++) {
            int ei = 2 * j + half_id;
            bool valid = ei < cnt;
            int sN = csr_src[beg + base + (valid ? ei : 0)];
            float t = als[(size_t)sN * 8 + ph] + ald_ph;
            float p = valid ? fexp2(lrelu2(t) - m0) : 0.0f;
            float2 hf = __half22float2(*(const __half2*)(h + (size_t)sN * 64 + 2 * l));
            ax += p * hf.x;
            ay += p * hf.y;
            s += p;
        }
    }
    ax += __shfl_xor(ax, 32);
    ay += __shfl_xor(ay, 32);
    s  += __shfl_xor(s, 32);
    if (half_id == 0) {
        float inv = 1.0f / (s + 1e-16f);
        float vx = ax * inv + bias[2 * l];
        float vy = ay * inv + bias[2 * l + 1];
        vx = vx > 0.0f ? vx : expm1f(vx);
        vy = vy > 0.0f ? vy : expm1f(vy);
        *(__half2*)&out[(size_t)node * 64 + 2 * l] = __floats2half2_rn(vx, vy);
    }
}

// ---------------- GAT layer 3 (H=1,C=40): 2 half-waves + log_softmax ----------------
__launch_bounds__(256)
__global__ void k_gat3h(const int* __restrict__ rowptr, const int* __restrict__ csr_src,
                        const __half* __restrict__ h, const float* __restrict__ als,
                        const float* __restrict__ ald, const float* __restrict__ bias,
                        float* __restrict__ out, int n) {
    const int lane = threadIdx.x & 63;
    const int node = blockIdx.x * 4 + (threadIdx.x >> 6);
    if (node >= n) return;
    const int beg = rowptr[node];
    const int deg = rowptr[node + 1] - beg;
    const int half_id = lane >> 5;
    const int l = lane & 31;
    const int cl = (l < 20) ? l : 0;  // channel pair (2cl, 2cl+1)
    const float ald_v = ald[node];
    const float m0 = lrelu2(als[node] + ald_v);

    float2 hv = __half22float2(*(const __half2*)(h + (size_t)node * 40 + 2 * cl));
    float ax = half_id ? 0.0f : hv.x;
    float ay = half_id ? 0.0f : hv.y;
    float s  = half_id ? 0.0f : 1.0f;

    for (int base = 0; base < deg; base += 64) {
        const int cnt = min(64, deg - base);
        const int iters = (cnt + 1) >> 1;
#pragma unroll 4
        for (int j = 0; j < iters; j++) {
            int ei = 2 * j + half_id;
            bool valid = ei < cnt;
            int sN = csr_src[beg + base + (valid ? ei : 0)];
            float t = als[sN] + ald_v;
            float p = valid ? fexp2(lrelu2(t) - m0) : 0.0f;
            float2 hf = __half22float2(*(const __half2*)(h + (size_t)sN * 40 + 2 * cl));
            ax += p * hf.x;
            ay += p * hf.y;
            s += p;
        }
    }
    ax += __shfl_xor(ax, 32);
    ay += __shfl_xor(ay, 32);
    s  += __shfl_xor(s, 32);
    float inv = 1.0f / (s + 1e-16f);
    float vx = ax * inv + bias[2 * cl];
    float vy = ay * inv + bias[2 * cl + 1];
    float mval = (l < 20) ? fmaxf(vx, vy) : -INFINITY;
#pragma unroll
    for (int off = 16; off > 0; off >>= 1) mval = fmaxf(mval, __shfl_xor(mval, off));
    float ex = (l < 20) ? __expf(vx - mval) + __expf(vy - mval) : 0.0f;
    float ss = ex;
#pragma unroll
    for (int off = 16; off > 0; off >>= 1) ss += __shfl_xor(ss, off);
    float ls = logf(ss);
    if (half_id == 0 && l < 20)
        *(float2*)&out[(size_t)node * 40 + 2 * l] = float2{vx - mval - ls, vy - mval - ls};
}

static inline int nblk(long long t, int b) { return (int)((t + b - 1) / b); }

extern "C" void kernel_launch(void* const* d_in, const int* in_sizes, int n_in,
                              void* d_out, int out_size, void* d_ws, size_t ws_size,
                              hipStream_t stream) {
    const float* x = (const float*)d_in[0];
    const int* eidx = (const int*)d_in[1];
    const int* seed_mask = (const int*)d_in[2];
    const float* W1 = (const float*)d_in[3];
    const float* a1s = (const float*)d_in[4];
    const float* a1d = (const float*)d_in[5];
    const float* b1 = (const float*)d_in[6];
    const float* W2 = (const float*)d_in[7];
    const float* a2s = (const float*)d_in[8];
    const float* a2d = (const float*)d_in[9];
    const float* b2 = (const float*)d_in[10];
    const float* W3 = (const float*)d_in[11];
    const float* a3s = (const float*)d_in[12];
    const float* a3d = (const float*)d_in[13];
    const float* b3 = (const float*)d_in[14];
    const float* Wg = (const float*)d_in[15];
    const float* bg = (const float*)d_in[16];

    const int n = in_sizes[0] / 128;        // 100000
    const long long E = in_sizes[1] / 2;    // 1600000
    const int E4 = (int)(E / 4);
    const int4* src4 = (const int4*)eidx;
    const int4* dst4 = (const int4*)(eidx + E);
    const int BINS = (n + NS - 1) >> NSB;   // 196 <= 256
    const int NW = (n + 31) / 32;

    char* ws = (char*)d_ws;
    size_t off = 0;
    auto alloc = [&](size_t bytes) -> void* {
        void* p = ws + off;
        off = (off + bytes + 255) & ~(size_t)255;
        return p;
    };
    int* dist    = (int*)alloc((size_t)n * 4);
    u32* rbits   = (u32*)alloc((size_t)NW * 4);
    u8* nbr      = (u8*)alloc((size_t)n);
    int* rowptr  = (int*)alloc((size_t)(n + 1) * 4);
    int* bincnt  = (int*)alloc(256 * 4);
    int* binbase = (int*)alloc(257 * 4);
    int* bincur  = (int*)alloc(256 * 4);
    int* csr_src = (int*)alloc((size_t)E * 4);
    float* als   = (float*)alloc((size_t)n * 8 * 4);
    float* ald   = (float*)alloc((size_t)n * 8 * 4);
    __half* hbuf = (__half*)alloc((size_t)n * 128 * 2);  // GEMM out (h)
    __half* abuf = (__half*)alloc((size_t)n * 128 * 2);  // GAT out (next A)
    int* pairs   = (int*)abuf;  // alias: pairs only live during CSR build
    float* out = (float*)d_out;

    const int BS = 256;

    // ---- CSR build: binned counting sort ----
    hipMemsetAsync(bincnt, 0, 256 * 4, stream);
    k_bfs_init<<<nblk(n, BS), BS, 0, stream>>>(seed_mask, dist, n);
    k_rbits_init<<<nblk(NW, BS), BS, 0, stream>>>(seed_mask, rbits, NW, n);
    k_bincount<<<nblk(E4, BS), BS, 0, stream>>>(dst4, bincnt, E4);
    k_binscan<<<1, 256, 0, stream>>>(bincnt, binbase, bincur, rowptr, BINS, (int)E, n);
    k_binscatter<<<nblk(E4, BS), BS, 0, stream>>>(src4, dst4, bincur, pairs, E4, BINS);
    k_binsort<<<BINS, 256, 0, stream>>>(pairs, binbase, rowptr, csr_src, n);

    // ---- BFS hierarchy via CSR (bitset reached) ----
    for (int h = 1; h <= MAXH; h++) {
        k_bfs_scan<<<nblk(n, BS), BS, 0, stream>>>(rowptr, csr_src, rbits, nbr, n);
        k_bfs_node<<<nblk(n, BS), BS, 0, stream>>>(rbits, dist, nbr, h, n);
    }

    // ---- Layer 1: aug(132) -> 8x8, ELU fused ----
    k_gemm_t<float, 128, 132, 64, 64, true, 8, 8, 256>
        <<<nblk(n, 64), 256, 0, stream>>>(x, W1, a1s, a1d, dist, hbuf, als, ald, n);
    k_gat1h<<<nblk(n, 4), 256, 0, stream>>>(rowptr, csr_src, hbuf, als, ald, b1, abuf, n);

    // ---- Layer 2: 64 -> 8x16, gate fused ----
    k_gemm_t<__half, 64, 64, 128, 128, false, 8, 16, 512>
        <<<nblk(n, 64), 512, 0, stream>>>(abuf, W2, a2s, a2d, nullptr, hbuf, als, ald, n);
    k_gat<8, 16, 2, 2, __half><<<nblk(n, 4), 256, 0, stream>>>(
        rowptr, csr_src, hbuf, als, ald, b2, dist, Wg, bg, abuf, n);

    // ---- Layer 3: 128 -> 1x40, log_softmax fused ----
    k_gemm_t<__half, 128, 128, 64, 40, false, 1, 40, 256>
        <<<nblk(n, 64), 256, 0, stream>>>(abuf, W3, a3s, a3d, nullptr, hbuf, als, ald, n);
    k_gat3h<<<nblk(n, 4), 256, 0, stream>>>(rowptr, csr_src, hbuf, als, ald, b3, out, n);
}

// Round 11
// 439.017 us; speedup vs baseline: 1.3887x; 1.2916x over previous
//
#include <hip/hip_runtime.h>
#include <hip/hip_bf16.h>
#include <hip/hip_fp16.h>
#include <math.h>

#define MAXH 3
#define NSB 9              // 512 nodes per bin
#define NS (1 << NSB)
#define SRCBITS 17         // n < 131072
#define SRCMASK ((1 << SRCBITS) - 1)
#define LOG2E 1.4426950408889634f
typedef unsigned int u32;
typedef unsigned char u8;
typedef unsigned short u16;

using bf16x8 = __attribute__((ext_vector_type(8))) short;
using f32x4  = __attribute__((ext_vector_type(4))) float;

__device__ __forceinline__ float lrelu2(float x) { return fmaxf(x, 0.2f * x); }
__device__ __forceinline__ float fexp2(float x) {
#if __has_builtin(__builtin_amdgcn_exp2f)
    return __builtin_amdgcn_exp2f(x);
#else
    return exp2f(x);
#endif
}
__device__ __forceinline__ u16 f2bf(float f) {  // RNE float->bf16
    u32 u = __float_as_uint(f);
    u32 r = ((u >> 16) & 1u) + 0x7fffu;
    return (u16)((u + r) >> 16);
}

// ---------------- BFS hierarchy (bitset reached, CSR in-neighbor scan) ----------------
__global__ void k_bfs_init(const int* __restrict__ seed_mask, int* dist, int n) {
    int i = blockIdx.x * blockDim.x + threadIdx.x;
    if (i < n) dist[i] = (seed_mask[i] == 0) ? 0 : (MAXH + 1);
}
__global__ void k_rbits_init(const int* __restrict__ seed_mask, u32* rbits, int nw, int n) {
    int w = blockIdx.x * blockDim.x + threadIdx.x;
    if (w < nw) {
        u32 b = 0;
        int base = w * 32;
        int lim = min(32, n - base);
        for (int j = 0; j < lim; j++)
            if (seed_mask[base + j] == 0) b |= (1u << j);
        rbits[w] = b;
    }
}
__global__ void k_bfs_scan(const int* __restrict__ rowptr, const int* __restrict__ csr_src,
                           const u32* __restrict__ rbits, u8* __restrict__ nbr, int n) {
    int i = blockIdx.x * blockDim.x + threadIdx.x;
    if (i < n) {
        if (!((rbits[i >> 5] >> (i & 31)) & 1u)) {
            int beg = rowptr[i], end = rowptr[i + 1];
            u8 f = 0;
            for (int k = beg; k < end; k++) {
                int s = csr_src[k];
                if ((rbits[s >> 5] >> (s & 31)) & 1u) { f = 1; break; }
            }
            nbr[i] = f;
        }
    }
}
__global__ void k_bfs_node(u32* rbits, int* dist, const u8* __restrict__ nbr, int h, int n) {
    int i = blockIdx.x * blockDim.x + threadIdx.x;
    if (i < n) {
        if (nbr[i] && !((rbits[i >> 5] >> (i & 31)) & 1u)) {
            dist[i] = h;
            atomicOr(&rbits[i >> 5], 1u << (i & 31));
        }
    }
}

// ---------------- CSR build: locality-binned 2-level counting sort ----------------
__global__ void k_bincount(const int4* __restrict__ dst4, int* bincnt, int E4) {
    __shared__ int cnt[256];
    int t = threadIdx.x;
    cnt[t] = 0;
    __syncthreads();
    int i = blockIdx.x * 256 + t;
    if (i < E4) {
        int4 d = dst4[i];
        atomicAdd(&cnt[d.x >> NSB], 1);
        atomicAdd(&cnt[d.y >> NSB], 1);
        atomicAdd(&cnt[d.z >> NSB], 1);
        atomicAdd(&cnt[d.w >> NSB], 1);
    }
    __syncthreads();
    if (cnt[t] > 0) atomicAdd(&bincnt[t], cnt[t]);
}

__global__ void k_binscan(const int* __restrict__ bincnt, int* binbase, int* bincur,
                          int* rowptr, int BINS, int E, int n) {
    __shared__ int sd[256];
    int t = threadIdx.x;
    int v = (t < BINS) ? bincnt[t] : 0;
    sd[t] = v;
    __syncthreads();
    for (int off = 1; off < 256; off <<= 1) {
        int add = (t >= off) ? sd[t - off] : 0;
        __syncthreads();
        sd[t] += add;
        __syncthreads();
    }
    int excl = sd[t] - v;
    if (t < BINS) { binbase[t] = excl; bincur[t] = excl; }
    if (t == 0) { binbase[BINS] = E; rowptr[n] = E; }
}

__global__ void k_binscatter(const int4* __restrict__ src4, const int4* __restrict__ dst4,
                             int* bincur, int* __restrict__ pairs, int E4, int BINS) {
    __shared__ int cnt[256], base[256];
    int t = threadIdx.x;
    cnt[t] = 0;
    __syncthreads();
    int i = blockIdx.x * 256 + t;
    int bin[4], rank[4], pack[4];
    bool valid = i < E4;
    if (valid) {
        int4 s = src4[i], d = dst4[i];
        bin[0] = d.x >> NSB; pack[0] = ((d.x & (NS - 1)) << SRCBITS) | s.x;
        bin[1] = d.y >> NSB; pack[1] = ((d.y & (NS - 1)) << SRCBITS) | s.y;
        bin[2] = d.z >> NSB; pack[2] = ((d.z & (NS - 1)) << SRCBITS) | s.z;
        bin[3] = d.w >> NSB; pack[3] = ((d.w & (NS - 1)) << SRCBITS) | s.w;
        rank[0] = atomicAdd(&cnt[bin[0]], 1);
        rank[1] = atomicAdd(&cnt[bin[1]], 1);
        rank[2] = atomicAdd(&cnt[bin[2]], 1);
        rank[3] = atomicAdd(&cnt[bin[3]], 1);
    }
    __syncthreads();
    if (t < BINS && cnt[t] > 0) base[t] = atomicAdd(&bincur[t], cnt[t]);
    __syncthreads();
    if (valid) {
        pairs[base[bin[0]] + rank[0]] = pack[0];
        pairs[base[bin[1]] + rank[1]] = pack[1];
        pairs[base[bin[2]] + rank[2]] = pack[2];
        pairs[base[bin[3]] + rank[3]] = pack[3];
    }
}

__global__ void k_binsort(const int* __restrict__ pairs, const int* __restrict__ binbase,
                          int* __restrict__ rowptr, int* __restrict__ csr_src, int n) {
    __shared__ int hist[NS];
    const int b = blockIdx.x, t = threadIdx.x;
    const int nbeg = b << NSB;
    const int ebeg = binbase[b];
    const int ecnt = binbase[b + 1] - ebeg;
    hist[t] = 0; hist[t + 256] = 0;
    __syncthreads();
    for (int i = t; i < ecnt; i += 256)
        atomicAdd(&hist[(u32)pairs[ebeg + i] >> SRCBITS], 1);
    for (int d = 1; d < NS; d <<= 1) {
        __syncthreads();
        int idx = (t + 1) * (d << 1) - 1;
        if (idx < NS) hist[idx] += hist[idx - d];
    }
    __syncthreads();
    if (t == 0) hist[NS - 1] = 0;
    for (int d = NS / 2; d >= 1; d >>= 1) {
        __syncthreads();
        int idx = (t + 1) * (d << 1) - 1;
        if (idx < NS) { int tmp = hist[idx - d]; hist[idx - d] = hist[idx]; hist[idx] += tmp; }
    }
    __syncthreads();
    int g0 = nbeg + t, g1 = nbeg + t + 256;
    if (g0 < n) rowptr[g0] = ebeg + hist[t];
    if (g1 < n) rowptr[g1] = ebeg + hist[t + 256];
    __syncthreads();
    for (int i = t; i < ecnt; i += 256) {
        int p = pairs[ebeg + i];
        int pos = atomicAdd(&hist[(u32)p >> SRCBITS], 1);
        csr_src[ebeg + pos] = p & SRCMASK;
    }
}

// ---------------- layer-1 vector GEMM (fp32 A + AUG), fp16 out, fused attn logits ----
template <int K, int KW, int MP, int MREAL, int AH, int AC, int THREADS>
__launch_bounds__(THREADS)
__global__ void k_gemm_t(const float* __restrict__ A, const float* __restrict__ W,
                         const float* __restrict__ a_s, const float* __restrict__ a_d,
                         const int* __restrict__ dist, __half* __restrict__ out,
                         float* __restrict__ als, float* __restrict__ ald, int n) {
    constexpr int COLT = MP / 4;
    constexpr int ROWT = THREADS / COLT;
    constexpr int RPT = 64 / ROWT;  // = 4
    constexpr int BK = 64;
    constexpr int SAP = BK + 4;
    __shared__ float sA[64 * SAP];
    __shared__ float sW[KW * MP];

    for (int i = threadIdx.x; i < KW * MP; i += THREADS) {
        int r = i / MP, c = i % MP;
        sW[i] = (c < MREAL) ? W[r * MREAL + c] : 0.0f;
    }
    const int tcol = threadIdx.x % COLT;
    const int trow = threadIdx.x / COLT;
    const int rowbase = blockIdx.x * 64;

    float4 acc[RPT];
#pragma unroll
    for (int r = 0; r < RPT; r++) acc[r] = float4{0.f, 0.f, 0.f, 0.f};

    for (int k0 = 0; k0 < K; k0 += BK) {
        __syncthreads();
        for (int i = threadIdx.x; i < 64 * (BK / 4); i += THREADS) {
            int r = i / (BK / 4), c4 = i % (BK / 4);
            int row = rowbase + r;
            float4 v = float4{0.f, 0.f, 0.f, 0.f};
            if (row < n) v = *(const float4*)&A[(size_t)row * K + k0 + c4 * 4];
            *(float4*)&sA[r * SAP + c4 * 4] = v;
        }
        __syncthreads();
#pragma unroll 2
        for (int k4 = 0; k4 < BK / 4; k4++) {
            float4 w0 = *(const float4*)&sW[(k0 + k4 * 4 + 0) * MP + tcol * 4];
            float4 w1 = *(const float4*)&sW[(k0 + k4 * 4 + 1) * MP + tcol * 4];
            float4 w2 = *(const float4*)&sW[(k0 + k4 * 4 + 2) * MP + tcol * 4];
            float4 w3 = *(const float4*)&sW[(k0 + k4 * 4 + 3) * MP + tcol * 4];
#pragma unroll
            for (int r = 0; r < RPT; r++) {
                float4 a = *(const float4*)&sA[(trow * RPT + r) * SAP + k4 * 4];
                acc[r].x += a.x * w0.x + a.y * w1.x + a.z * w2.x + a.w * w3.x;
                acc[r].y += a.x * w0.y + a.y * w1.y + a.z * w2.y + a.w * w3.y;
                acc[r].z += a.x * w0.z + a.y * w1.z + a.z * w2.z + a.w * w3.z;
                acc[r].w += a.x * w0.w + a.y * w1.w + a.z * w2.w + a.w * w3.w;
            }
        }
    }

    float as_[4], ad_[4];
#pragma unroll
    for (int j = 0; j < 4; j++) {
        int col = tcol * 4 + j;
        bool ok = col < MREAL;
        as_[j] = ok ? a_s[col] * LOG2E : 0.0f;
        ad_[j] = ok ? a_d[col] * LOG2E : 0.0f;
    }
    constexpr int TPH = AC / 4;
    constexpr int RW = (TPH & (TPH - 1)) ? 16 : TPH;
    const int head = (tcol * 4) / AC;

#pragma unroll
    for (int r = 0; r < RPT; r++) {
        int row = rowbase + trow * RPT + r;
        if (row < n) {
            int d = dist[row];
            if (d <= MAXH) {
                float4 wd = *(const float4*)&sW[(K + d) * MP + tcol * 4];
                acc[r].x += wd.x; acc[r].y += wd.y; acc[r].z += wd.z; acc[r].w += wd.w;
            }
        }
        float ps = acc[r].x * as_[0] + acc[r].y * as_[1] + acc[r].z * as_[2] + acc[r].w * as_[3];
        float pd = acc[r].x * ad_[0] + acc[r].y * ad_[1] + acc[r].z * ad_[2] + acc[r].w * ad_[3];
#pragma unroll
        for (int o = 1; o < RW; o <<= 1) {
            ps += __shfl_xor(ps, o);
            pd += __shfl_xor(pd, o);
        }
        if (row < n) {
            if ((tcol % RW) == 0) {
                als[(size_t)row * AH + head] = ps;
                ald[(size_t)row * AH + head] = pd;
            }
            if (tcol * 4 + 3 < MREAL) {
                __half2* op = (__half2*)&out[(size_t)row * MREAL + tcol * 4];
                op[0] = __floats2half2_rn(acc[r].x, acc[r].y);
                op[1] = __floats2half2_rn(acc[r].z, acc[r].w);
            }
        }
    }
}

// ---------------- MFMA GEMM (A bf16) with fused attn-logit columns ----------------
// out(n,NREAL) fp16 = A(n,K) @ W(K,NREAL); extra col-tile holds [Ws | Wd] so that
// als/ald = A @ Ws/Wd (LOG2E prefolded). NTT tiles incl. attn tile; SK = padded K stride.
template <int K, int NREAL, int NTT, int AH, int C, int SK, int MBW>
__launch_bounds__(256)
__global__ void k_gemm_mfma(const u16* __restrict__ A, const float* __restrict__ W,
                            const float* __restrict__ a_s, const float* __restrict__ a_d,
                            __half* __restrict__ out, float* __restrict__ als,
                            float* __restrict__ ald, int n) {
    constexpr int KT = K / 32;
    constexpr int NTCOL = (NTT - 1) * 16;
    __shared__ u16 WT[NTT * 16 * SK];
    for (int idx = threadIdx.x; idx < NTT * 16 * K; idx += 256) {
        int c = idx / K, k = idx % K;
        float v = 0.0f;
        if (c < NREAL) {
            v = W[k * NREAL + c];
        } else if (c >= NTCOL && c < NTCOL + 2 * AH) {
            int j = (c - NTCOL) % AH;
            const float* aw = (c < NTCOL + AH) ? a_s : a_d;
            float accv = 0.0f;
            for (int cc = 0; cc < C; cc++) accv += W[k * NREAL + j * C + cc] * aw[j * C + cc];
            v = accv * LOG2E;
        }
        WT[c * SK + k] = f2bf(v);
    }
    __syncthreads();

    const int lane = threadIdx.x & 63;
    const int l15 = lane & 15;
    const int kg = lane >> 4;  // 0..3
    const int wid = blockIdx.x * 4 + (threadIdx.x >> 6);

    bf16x8 bfr[NTT][KT];
#pragma unroll
    for (int nt = 0; nt < NTT; nt++)
#pragma unroll
        for (int kt = 0; kt < KT; kt++)
            bfr[nt][kt] = *(const bf16x8*)&WT[(nt * 16 + l15) * SK + kt * 32 + kg * 8];

    for (int mb = 0; mb < MBW; mb++) {
        const int rowbase = (wid * MBW + mb) * 16;
        if (rowbase >= n) break;
        bf16x8 af[KT];
#pragma unroll
        for (int kt = 0; kt < KT; kt++)
            af[kt] = *(const bf16x8*)&A[(size_t)(rowbase + l15) * K + kt * 32 + kg * 8];
        f32x4 acc[NTT];
#pragma unroll
        for (int nt = 0; nt < NTT; nt++) acc[nt] = f32x4{0.f, 0.f, 0.f, 0.f};
#pragma unroll
        for (int kt = 0; kt < KT; kt++)
#pragma unroll
            for (int nt = 0; nt < NTT; nt++)
                acc[nt] = __builtin_amdgcn_mfma_f32_16x16x32_bf16(af[kt], bfr[nt][kt],
                                                                  acc[nt], 0, 0, 0);
        // D layout (HW-verified): col = lane&15, row = (lane>>4)*4 + reg
#pragma unroll
        for (int nt = 0; nt < NTT - 1; nt++) {
            int c = nt * 16 + l15;
            if (c < NREAL) {
#pragma unroll
                for (int r = 0; r < 4; r++) {
                    int row = rowbase + kg * 4 + r;
                    out[(size_t)row * NREAL + c] = __float2half(acc[nt][r]);
                }
            }
        }
#pragma unroll
        for (int r = 0; r < 4; r++) {
            int row = rowbase + kg * 4 + r;
            float v = acc[NTT - 1][r];
            if (l15 < AH) als[(size_t)row * AH + l15] = v;
            else if (l15 < 2 * AH) ald[(size_t)row * AH + (l15 - AH)] = v;
        }
    }
}

// ---------------- fused GAT (round-8 form): single-pass no-max softmax, readlane ----
// MODE: 1=ELU (out bf16), 2=gate (out bf16), 3=log_softmax (out f32)
template <int H, int C, int CH, int MODE, typename OT>
__launch_bounds__(256)
__global__ void k_gat(const int* __restrict__ rowptr, const int* __restrict__ csr_src,
                      const __half* __restrict__ h, const float* __restrict__ als,
                      const float* __restrict__ ald, const float* __restrict__ bias,
                      const int* __restrict__ dist, const float* __restrict__ Wg,
                      const float* __restrict__ bg, OT* __restrict__ out, int n) {
    constexpr int TOT = H * C;
    constexpr int NL = TOT / CH;
    const int lane = threadIdx.x & 63;
    const int node = blockIdx.x * 4 + (threadIdx.x >> 6);
    if (node >= n) return;
    const int beg = rowptr[node];
    const int deg = rowptr[node + 1] - beg;

    const int cl = (lane < NL) ? lane : 0;
    const int hd = (cl * CH) / C;
    const float ald_hd = ald[(size_t)node * H + hd];
    const float m0 = lrelu2(als[(size_t)node * H + hd] + ald_hd);

    float s = 1.0f, ax, ay = 0.0f;
    if (CH == 2) {
        float2 hv = __half22float2(*(const __half2*)(h + (size_t)node * TOT + cl * 2));
        ax = hv.x; ay = hv.y;
    } else {
        ax = __half2float(h[(size_t)node * TOT + cl]);
    }

    auto body = [&](int sN) {
        float t = als[(size_t)sN * H + hd] + ald_hd;
        float p = fexp2(lrelu2(t) - m0);
        s += p;
        if (CH == 2) {
            float2 hf = __half22float2(*(const __half2*)(h + (size_t)sN * TOT + cl * 2));
            ax += p * hf.x;
            ay += p * hf.y;
        } else {
            ax += p * __half2float(h[(size_t)sN * TOT + cl]);
        }
    };

    for (int base = 0; base < deg; base += 64) {
        const int myE = base + lane;
        int sReg = (myE < deg) ? csr_src[beg + myE] : 0;
        const int cnt = min(64, deg - base);
        int e = 0;
        for (; e + 4 <= cnt; e += 4) {
            body(__builtin_amdgcn_readlane(sReg, e));
            body(__builtin_amdgcn_readlane(sReg, e + 1));
            body(__builtin_amdgcn_readlane(sReg, e + 2));
            body(__builtin_amdgcn_readlane(sReg, e + 3));
        }
        for (; e < cnt; e++) body(__builtin_amdgcn_readlane(sReg, e));
    }

    const float inv = 1.0f / (s + 1e-16f);
    float vx = ax * inv + bias[cl * CH];
    float vy = (CH == 2) ? (ay * inv + bias[cl * CH + 1]) : 0.0f;

    if (MODE == 1) {  // ELU -> bf16
        vx = vx > 0.0f ? vx : expm1f(vx);
        ((u16*)out)[(size_t)node * TOT + cl] = f2bf(vx);
    } else if (MODE == 2) {  // gate -> bf16
        float2 wg = *(const float2*)&Wg[cl * 2];
        float part = vx * wg.x + vy * wg.y;
#pragma unroll
        for (int off = 32; off > 0; off >>= 1) part += __shfl_xor(part, off);
        int d = dist[node];
        float hop = (d <= MAXH) ? (float)d : 0.0f;
        float g = 1.0f / (1.0f + __expf(-(part + hop * Wg[128] + bg[0])));
        ushort2 w;
        w.x = f2bf(vx * g);
        w.y = f2bf(vy * g);
        *(ushort2*)&((u16*)out)[(size_t)node * TOT + cl * 2] = w;
    } else if (MODE == 3) {  // log_softmax -> fp32
        float v = (lane < NL) ? vx : -INFINITY;
        float mm = v;
#pragma unroll
        for (int off = 32; off > 0; off >>= 1) mm = fmaxf(mm, __shfl_xor(mm, off));
        float ex = (lane < NL) ? __expf(v - mm) : 0.0f;
        float ss = ex;
#pragma unroll
        for (int off = 32; off > 0; off >>= 1) ss += __shfl_xor(ss, off);
        float ls = logf(ss);
        if (lane < NL) ((float*)out)[(size_t)node * TOT + cl] = v - mm - ls;
    }
}

static inline int nblk(long long t, int b) { return (int)((t + b - 1) / b); }

extern "C" void kernel_launch(void* const* d_in, const int* in_sizes, int n_in,
                              void* d_out, int out_size, void* d_ws, size_t ws_size,
                              hipStream_t stream) {
    const float* x = (const float*)d_in[0];
    const int* eidx = (const int*)d_in[1];
    const int* seed_mask = (const int*)d_in[2];
    const float* W1 = (const float*)d_in[3];
    const float* a1s = (const float*)d_in[4];
    const float* a1d = (const float*)d_in[5];
    const float* b1 = (const float*)d_in[6];
    const float* W2 = (const float*)d_in[7];
    const float* a2s = (const float*)d_in[8];
    const float* a2d = (const float*)d_in[9];
    const float* b2 = (const float*)d_in[10];
    const float* W3 = (const float*)d_in[11];
    const float* a3s = (const float*)d_in[12];
    const float* a3d = (const float*)d_in[13];
    const float* b3 = (const float*)d_in[14];
    const float* Wg = (const float*)d_in[15];
    const float* bg = (const float*)d_in[16];

    const int n = in_sizes[0] / 128;        // 100000
    const long long E = in_sizes[1] / 2;    // 1600000
    const int E4 = (int)(E / 4);
    const int4* src4 = (const int4*)eidx;
    const int4* dst4 = (const int4*)(eidx + E);
    const int BINS = (n + NS - 1) >> NSB;   // 196 <= 256
    const int NW = (n + 31) / 32;

    char* ws = (char*)d_ws;
    size_t off = 0;
    auto alloc = [&](size_t bytes) -> void* {
        void* p = ws + off;
        off = (off + bytes + 255) & ~(size_t)255;
        return p;
    };
    int* dist    = (int*)alloc((size_t)n * 4);
    u32* rbits   = (u32*)alloc((size_t)NW * 4);
    u8* nbr      = (u8*)alloc((size_t)n);
    int* rowptr  = (int*)alloc((size_t)(n + 1) * 4);
    int* bincnt  = (int*)alloc(256 * 4);
    int* binbase = (int*)alloc(257 * 4);
    int* bincur  = (int*)alloc(256 * 4);
    int* csr_src = (int*)alloc((size_t)E * 4);
    float* als   = (float*)alloc((size_t)n * 8 * 4);
    float* ald   = (float*)alloc((size_t)n * 8 * 4);
    __half* hbuf = (__half*)alloc((size_t)n * 128 * 2);  // GEMM out (h), fp16
    u16* abuf    = (u16*)alloc((size_t)n * 128 * 2);     // GAT out (next GEMM A), bf16
    int* pairs   = (int*)abuf;  // alias: pairs only live during CSR build
    float* out = (float*)d_out;

    const int BS = 256;

    // ---- CSR build: binned counting sort ----
    hipMemsetAsync(bincnt, 0, 256 * 4, stream);
    k_bfs_init<<<nblk(n, BS), BS, 0, stream>>>(seed_mask, dist, n);
    k_rbits_init<<<nblk(NW, BS), BS, 0, stream>>>(seed_mask, rbits, NW, n);
    k_bincount<<<nblk(E4, BS), BS, 0, stream>>>(dst4, bincnt, E4);
    k_binscan<<<1, 256, 0, stream>>>(bincnt, binbase, bincur, rowptr, BINS, (int)E, n);
    k_binscatter<<<nblk(E4, BS), BS, 0, stream>>>(src4, dst4, bincur, pairs, E4, BINS);
    k_binsort<<<BINS, 256, 0, stream>>>(pairs, binbase, rowptr, csr_src, n);

    // ---- BFS hierarchy via CSR (bitset reached) ----
    for (int h = 1; h <= MAXH; h++) {
        k_bfs_scan<<<nblk(n, BS), BS, 0, stream>>>(rowptr, csr_src, rbits, nbr, n);
        k_bfs_node<<<nblk(n, BS), BS, 0, stream>>>(rbits, dist, nbr, h, n);
    }

    const int mblocks = (n + 15) / 16;
    const int gmf = (mblocks + 15) / 16;   // 4 waves x MBW=4 m-blocks per block

    // ---- Layer 1: aug(132) -> 8x8, ELU fused (vector GEMM, fp32 A) ----
    k_gemm_t<128, 132, 64, 64, 8, 8, 256>
        <<<nblk(n, 64), 256, 0, stream>>>(x, W1, a1s, a1d, dist, hbuf, als, ald, n);
    k_gat<8, 8, 1, 1, u16><<<nblk(n, 4), 256, 0, stream>>>(
        rowptr, csr_src, hbuf, als, ald, b1, nullptr, nullptr, nullptr, abuf, n);

    // ---- Layer 2: 64 -> 8x16, gate fused (MFMA GEMM, bf16 A) ----
    k_gemm_mfma<64, 128, 9, 8, 16, 72, 4>
        <<<gmf, 256, 0, stream>>>(abuf, W2, a2s, a2d, hbuf, als, ald, n);
    k_gat<8, 16, 2, 2, u16><<<nblk(n, 4), 256, 0, stream>>>(
        rowptr, csr_src, hbuf, als, ald, b2, dist, Wg, bg, abuf, n);

    // ---- Layer 3: 128 -> 1x40, log_softmax fused (MFMA GEMM, bf16 A) ----
    k_gemm_mfma<128, 40, 4, 1, 40, 136, 4>
        <<<gmf, 256, 0, stream>>>(abuf, W3, a3s, a3d, hbuf, als, ald, n);
    k_gat<1, 40, 1, 3, float><<<nblk(n, 4), 256, 0, stream>>>(
        rowptr, csr_src, hbuf, als, ald, b3, nullptr, nullptr, nullptr, out, n);
}

// Round 12
// 438.221 us; speedup vs baseline: 1.3912x; 1.0018x over previous
//
#include <hip/hip_runtime.h>
#include <hip/hip_bf16.h>
#include <hip/hip_fp16.h>
#include <math.h>

#define MAXH 3
#define NSB 9              // 512 nodes per bin
#define NS (1 << NSB)
#define SRCBITS 17         // n < 131072
#define SRCMASK ((1 << SRCBITS) - 1)
#define LOG2E 1.4426950408889634f
typedef unsigned int u32;
typedef unsigned char u8;
typedef unsigned short u16;

using bf16x8 = __attribute__((ext_vector_type(8))) short;
using f32x4  = __attribute__((ext_vector_type(4))) float;

__device__ __forceinline__ float fexp2(float x) {
#if __has_builtin(__builtin_amdgcn_exp2f)
    return __builtin_amdgcn_exp2f(x);
#else
    return exp2f(x);
#endif
}
__device__ __forceinline__ u16 f2bf(float f) {  // RNE float->bf16
    u32 u = __float_as_uint(f);
    u32 r = ((u >> 16) & 1u) + 0x7fffu;
    return (u16)((u + r) >> 16);
}

// ---------------- BFS hierarchy (bitset reached, CSR in-neighbor scan) ----------------
__global__ void k_bfs_init(const int* __restrict__ seed_mask, int* dist, int n) {
    int i = blockIdx.x * blockDim.x + threadIdx.x;
    if (i < n) dist[i] = (seed_mask[i] == 0) ? 0 : (MAXH + 1);
}
__global__ void k_rbits_init(const int* __restrict__ seed_mask, u32* rbits, int nw, int n) {
    int w = blockIdx.x * blockDim.x + threadIdx.x;
    if (w < nw) {
        u32 b = 0;
        int base = w * 32;
        int lim = min(32, n - base);
        for (int j = 0; j < lim; j++)
            if (seed_mask[base + j] == 0) b |= (1u << j);
        rbits[w] = b;
    }
}
__global__ void k_bfs_scan(const int* __restrict__ rowptr, const int* __restrict__ csr_src,
                           const u32* __restrict__ rbits, u8* __restrict__ nbr, int n) {
    int i = blockIdx.x * blockDim.x + threadIdx.x;
    if (i < n) {
        if (!((rbits[i >> 5] >> (i & 31)) & 1u)) {
            int beg = rowptr[i], end = rowptr[i + 1];
            u8 f = 0;
            for (int k = beg; k < end; k++) {
                int s = csr_src[k];
                if ((rbits[s >> 5] >> (s & 31)) & 1u) { f = 1; break; }
            }
            nbr[i] = f;
        }
    }
}
__global__ void k_bfs_node(u32* rbits, int* dist, const u8* __restrict__ nbr, int h, int n) {
    int i = blockIdx.x * blockDim.x + threadIdx.x;
    if (i < n) {
        if (nbr[i] && !((rbits[i >> 5] >> (i & 31)) & 1u)) {
            dist[i] = h;
            atomicOr(&rbits[i >> 5], 1u << (i & 31));
        }
    }
}

// ---------------- CSR build: locality-binned 2-level counting sort ----------------
__global__ void k_bincount(const int4* __restrict__ dst4, int* bincnt, int E4) {
    __shared__ int cnt[256];
    int t = threadIdx.x;
    cnt[t] = 0;
    __syncthreads();
    int i = blockIdx.x * 256 + t;
    if (i < E4) {
        int4 d = dst4[i];
        atomicAdd(&cnt[d.x >> NSB], 1);
        atomicAdd(&cnt[d.y >> NSB], 1);
        atomicAdd(&cnt[d.z >> NSB], 1);
        atomicAdd(&cnt[d.w >> NSB], 1);
    }
    __syncthreads();
    if (cnt[t] > 0) atomicAdd(&bincnt[t], cnt[t]);
}

__global__ void k_binscan(const int* __restrict__ bincnt, int* binbase, int* bincur,
                          int* rowptr, int BINS, int E, int n) {
    __shared__ int sd[256];
    int t = threadIdx.x;
    int v = (t < BINS) ? bincnt[t] : 0;
    sd[t] = v;
    __syncthreads();
    for (int off = 1; off < 256; off <<= 1) {
        int add = (t >= off) ? sd[t - off] : 0;
        __syncthreads();
        sd[t] += add;
        __syncthreads();
    }
    int excl = sd[t] - v;
    if (t < BINS) { binbase[t] = excl; bincur[t] = excl; }
    if (t == 0) { binbase[BINS] = E; rowptr[n] = E; }
}

__global__ void k_binscatter(const int4* __restrict__ src4, const int4* __restrict__ dst4,
                             int* bincur, int* __restrict__ pairs, int E4, int BINS) {
    __shared__ int cnt[256], base[256];
    int t = threadIdx.x;
    cnt[t] = 0;
    __syncthreads();
    int i = blockIdx.x * 256 + t;
    int bin[4], rank[4], pack[4];
    bool valid = i < E4;
    if (valid) {
        int4 s = src4[i], d = dst4[i];
        bin[0] = d.x >> NSB; pack[0] = ((d.x & (NS - 1)) << SRCBITS) | s.x;
        bin[1] = d.y >> NSB; pack[1] = ((d.y & (NS - 1)) << SRCBITS) | s.y;
        bin[2] = d.z >> NSB; pack[2] = ((d.z & (NS - 1)) << SRCBITS) | s.z;
        bin[3] = d.w >> NSB; pack[3] = ((d.w & (NS - 1)) << SRCBITS) | s.w;
        rank[0] = atomicAdd(&cnt[bin[0]], 1);
        rank[1] = atomicAdd(&cnt[bin[1]], 1);
        rank[2] = atomicAdd(&cnt[bin[2]], 1);
        rank[3] = atomicAdd(&cnt[bin[3]], 1);
    }
    __syncthreads();
    if (t < BINS && cnt[t] > 0) base[t] = atomicAdd(&bincur[t], cnt[t]);
    __syncthreads();
    if (valid) {
        pairs[base[bin[0]] + rank[0]] = pack[0];
        pairs[base[bin[1]] + rank[1]] = pack[1];
        pairs[base[bin[2]] + rank[2]] = pack[2];
        pairs[base[bin[3]] + rank[3]] = pack[3];
    }
}

__global__ void k_binsort(const int* __restrict__ pairs, const int* __restrict__ binbase,
                          int* __restrict__ rowptr, int* __restrict__ csr_src, int n) {
    __shared__ int hist[NS];
    const int b = blockIdx.x, t = threadIdx.x;
    const int nbeg = b << NSB;
    const int ebeg = binbase[b];
    const int ecnt = binbase[b + 1] - ebeg;
    hist[t] = 0; hist[t + 256] = 0;
    __syncthreads();
    for (int i = t; i < ecnt; i += 256)
        atomicAdd(&hist[(u32)pairs[ebeg + i] >> SRCBITS], 1);
    for (int d = 1; d < NS; d <<= 1) {
        __syncthreads();
        int idx = (t + 1) * (d << 1) - 1;
        if (idx < NS) hist[idx] += hist[idx - d];
    }
    __syncthreads();
    if (t == 0) hist[NS - 1] = 0;
    for (int d = NS / 2; d >= 1; d >>= 1) {
        __syncthreads();
        int idx = (t + 1) * (d << 1) - 1;
        if (idx < NS) { int tmp = hist[idx - d]; hist[idx - d] = hist[idx]; hist[idx] += tmp; }
    }
    __syncthreads();
    int g0 = nbeg + t, g1 = nbeg + t + 256;
    if (g0 < n) rowptr[g0] = ebeg + hist[t];
    if (g1 < n) rowptr[g1] = ebeg + hist[t + 256];
    __syncthreads();
    for (int i = t; i < ecnt; i += 256) {
        int p = pairs[ebeg + i];
        int pos = atomicAdd(&hist[(u32)p >> SRCBITS], 1);
        csr_src[ebeg + pos] = p & SRCMASK;
    }
}

// ---------------- layer-1 MFMA GEMM: fp32 A converted to bf16 in LDS, AUG epilogue ----
// out(n,64) fp16 = [x | onehot(dist)] @ W1(132,64); attn tile cols 64..79 = [Ws|Wd].
template <int SK, int MBW>
__launch_bounds__(256)
__global__ void k_gemm_mfma1(const float* __restrict__ A, const float* __restrict__ W,
                             const float* __restrict__ a_s, const float* __restrict__ a_d,
                             const int* __restrict__ dist, __half* __restrict__ out,
                             float* __restrict__ als, float* __restrict__ ald, int n) {
    constexpr int K = 128, NREAL = 64, NTT = 5, AH = 8, C = 8;
    constexpr int KT = K / 32;            // 4
    constexpr int NTCOL = (NTT - 1) * 16; // 64
    __shared__ u16 WT[NTT * 16 * SK];
    __shared__ u16 sAW[4][16 * SK];
    __shared__ float sAug[4][64];
    __shared__ float sAugA[4][16];

    for (int idx = threadIdx.x; idx < NTT * 16 * K; idx += 256) {
        int c = idx / K, k = idx % K;
        float v;
        if (c < NREAL) {
            v = W[k * NREAL + c];
        } else {
            int j = (c - NTCOL) & 7;
            const float* aw = (c < NTCOL + AH) ? a_s : a_d;
            float accv = 0.0f;
            for (int cc = 0; cc < C; cc++) accv += W[k * NREAL + j * C + cc] * aw[j * C + cc];
            v = accv * LOG2E;
        }
        WT[c * SK + k] = f2bf(v);
    }
    {
        int t = threadIdx.x;
        int d = t >> 6, c = t & 63;
        sAug[d][c] = W[(K + d) * NREAL + c];      // all 256 threads cover 4x64
        if (t < 64) {
            int dd = t >> 4, j = t & 15;
            int hh = j & 7;
            const float* aw = (j < 8) ? a_s : a_d;
            float accv = 0.0f;
            for (int cc = 0; cc < C; cc++)
                accv += W[(K + dd) * NREAL + hh * C + cc] * aw[hh * C + cc];
            sAugA[dd][j] = accv * LOG2E;
        }
    }
    __syncthreads();

    const int lane = threadIdx.x & 63;
    const int l15 = lane & 15;
    const int kg = lane >> 4;
    const int w = threadIdx.x >> 6;
    const int wid = blockIdx.x * 4 + w;

    bf16x8 bfr[NTT][KT];
#pragma unroll
    for (int nt = 0; nt < NTT; nt++)
#pragma unroll
        for (int kt = 0; kt < KT; kt++)
            bfr[nt][kt] = *(const bf16x8*)&WT[(nt * 16 + l15) * SK + kt * 32 + kg * 8];

    for (int mb = 0; mb < MBW; mb++) {
        const int rowbase = (wid * MBW + mb) * 16;
        if (rowbase >= n) break;
        // stage 16 fp32 rows -> bf16 LDS (wave-private region; n%16==0 so rows valid)
        {
            int r = lane >> 2, c4b = lane & 3;
            const float* xr = A + (size_t)(rowbase + r) * K;
#pragma unroll
            for (int j = 0; j < 8; j++) {
                int c4 = c4b + j * 4;
                float4 v = *(const float4*)&xr[c4 * 4];
                ushort4 o;
                o.x = f2bf(v.x); o.y = f2bf(v.y); o.z = f2bf(v.z); o.w = f2bf(v.w);
                *(ushort4*)&sAW[w][r * SK + c4 * 4] = o;
            }
        }
        bf16x8 af[KT];
#pragma unroll
        for (int kt = 0; kt < KT; kt++)
            af[kt] = *(const bf16x8*)&sAW[w][l15 * SK + kt * 32 + kg * 8];
        f32x4 acc[NTT];
#pragma unroll
        for (int nt = 0; nt < NTT; nt++) acc[nt] = f32x4{0.f, 0.f, 0.f, 0.f};
#pragma unroll
        for (int kt = 0; kt < KT; kt++)
#pragma unroll
            for (int nt = 0; nt < NTT; nt++)
                acc[nt] = __builtin_amdgcn_mfma_f32_16x16x32_bf16(af[kt], bfr[nt][kt],
                                                                  acc[nt], 0, 0, 0);
        int rows[4], dd[4];
#pragma unroll
        for (int r = 0; r < 4; r++) {
            rows[r] = rowbase + kg * 4 + r;
            dd[r] = dist[rows[r]];
        }
#pragma unroll
        for (int nt = 0; nt < NTT - 1; nt++) {
            int c = nt * 16 + l15;
#pragma unroll
            for (int r = 0; r < 4; r++) {
                float v = acc[nt][r];
                if (dd[r] <= MAXH) v += sAug[dd[r]][c];
                out[(size_t)rows[r] * NREAL + c] = __float2half(v);
            }
        }
#pragma unroll
        for (int r = 0; r < 4; r++) {
            float v = acc[NTT - 1][r];
            if (dd[r] <= MAXH) v += sAugA[dd[r]][l15];
            if (l15 < AH) als[(size_t)rows[r] * AH + l15] = v;
            else ald[(size_t)rows[r] * AH + (l15 - AH)] = v;
        }
    }
}

// ---------------- MFMA GEMM (A bf16) with fused attn-logit columns ----------------
template <int K, int NREAL, int NTT, int AH, int C, int SK, int MBW>
__launch_bounds__(256)
__global__ void k_gemm_mfma(const u16* __restrict__ A, const float* __restrict__ W,
                            const float* __restrict__ a_s, const float* __restrict__ a_d,
                            __half* __restrict__ out, float* __restrict__ als,
                            float* __restrict__ ald, int n) {
    constexpr int KT = K / 32;
    constexpr int NTCOL = (NTT - 1) * 16;
    __shared__ u16 WT[NTT * 16 * SK];
    for (int idx = threadIdx.x; idx < NTT * 16 * K; idx += 256) {
        int c = idx / K, k = idx % K;
        float v = 0.0f;
        if (c < NREAL) {
            v = W[k * NREAL + c];
        } else if (c >= NTCOL && c < NTCOL + 2 * AH) {
            int j = (c - NTCOL) % AH;
            const float* aw = (c < NTCOL + AH) ? a_s : a_d;
            float accv = 0.0f;
            for (int cc = 0; cc < C; cc++) accv += W[k * NREAL + j * C + cc] * aw[j * C + cc];
            v = accv * LOG2E;
        }
        WT[c * SK + k] = f2bf(v);
    }
    __syncthreads();

    const int lane = threadIdx.x & 63;
    const int l15 = lane & 15;
    const int kg = lane >> 4;
    const int wid = blockIdx.x * 4 + (threadIdx.x >> 6);

    bf16x8 bfr[NTT][KT];
#pragma unroll
    for (int nt = 0; nt < NTT; nt++)
#pragma unroll
        for (int kt = 0; kt < KT; kt++)
            bfr[nt][kt] = *(const bf16x8*)&WT[(nt * 16 + l15) * SK + kt * 32 + kg * 8];

    for (int mb = 0; mb < MBW; mb++) {
        const int rowbase = (wid * MBW + mb) * 16;
        if (rowbase >= n) break;
        bf16x8 af[KT];
#pragma unroll
        for (int kt = 0; kt < KT; kt++)
            af[kt] = *(const bf16x8*)&A[(size_t)(rowbase + l15) * K + kt * 32 + kg * 8];
        f32x4 acc[NTT];
#pragma unroll
        for (int nt = 0; nt < NTT; nt++) acc[nt] = f32x4{0.f, 0.f, 0.f, 0.f};
#pragma unroll
        for (int kt = 0; kt < KT; kt++)
#pragma unroll
            for (int nt = 0; nt < NTT; nt++)
                acc[nt] = __builtin_amdgcn_mfma_f32_16x16x32_bf16(af[kt], bfr[nt][kt],
                                                                  acc[nt], 0, 0, 0);
        // D layout (HW-verified): col = lane&15, row = (lane>>4)*4 + reg
#pragma unroll
        for (int nt = 0; nt < NTT - 1; nt++) {
            int c = nt * 16 + l15;
            if (c < NREAL) {
#pragma unroll
                for (int r = 0; r < 4; r++) {
                    int row = rowbase + kg * 4 + r;
                    out[(size_t)row * NREAL + c] = __float2half(acc[nt][r]);
                }
            }
        }
#pragma unroll
        for (int r = 0; r < 4; r++) {
            int row = rowbase + kg * 4 + r;
            float v = acc[NTT - 1][r];
            if (l15 < AH) als[(size_t)row * AH + l15] = v;
            else if (l15 < 2 * AH) ald[(size_t)row * AH + (l15 - AH)] = v;
        }
    }
}

// ---------------- fused GAT (round-8 form): single-pass no-max softmax, readlane ----
// logit trick: lrelu(als+ald)-m0 == max(als+c0, 0.2*als+c1). MODE2 accumulates half2.
// MODE: 1=ELU (out bf16), 2=gate (out bf16), 3=log_softmax (out f32)
template <int H, int C, int CH, int MODE, typename OT>
__launch_bounds__(256)
__global__ void k_gat(const int* __restrict__ rowptr, const int* __restrict__ csr_src,
                      const __half* __restrict__ h, const float* __restrict__ als,
                      const float* __restrict__ ald, const float* __restrict__ bias,
                      const int* __restrict__ dist, const float* __restrict__ Wg,
                      const float* __restrict__ bg, OT* __restrict__ out, int n) {
    constexpr int TOT = H * C;
    constexpr int NL = TOT / CH;
    const int lane = threadIdx.x & 63;
    const int node = blockIdx.x * 4 + (threadIdx.x >> 6);
    if (node >= n) return;
    const int beg = rowptr[node];
    const int deg = rowptr[node + 1] - beg;

    const int cl = (lane < NL) ? lane : 0;
    const int hd = (cl * CH) / C;
    const float ald_hd = ald[(size_t)node * H + hd];
    const float t0 = als[(size_t)node * H + hd] + ald_hd;
    const float m0 = fmaxf(t0, 0.2f * t0);
    const float c0 = ald_hd - m0;
    const float c1 = 0.2f * ald_hd - m0;

    float s = 1.0f;
    float ax = 0.0f, ay = 0.0f;
    __half2 acc2;
    if (MODE == 2) {
        acc2 = *(const __half2*)(h + (size_t)node * TOT + cl * 2);  // self, weight 1
    } else {
        ax = __half2float(h[(size_t)node * TOT + cl]);
    }

    auto body = [&](int sN) {
        float a = als[(size_t)sN * H + hd];
        float v = fmaxf(a + c0, fmaf(a, 0.2f, c1));
        float p = fexp2(v);
        s += p;
        if (MODE == 2) {
            __half2 ph = __float2half2_rn(p);
            acc2 = __hfma2(ph, *(const __half2*)(h + (size_t)sN * TOT + cl * 2), acc2);
        } else {
            ax += p * __half2float(h[(size_t)sN * TOT + cl]);
        }
    };

    for (int base = 0; base < deg; base += 64) {
        const int myE = base + lane;
        int sReg = (myE < deg) ? csr_src[beg + myE] : 0;
        const int cnt = min(64, deg - base);
        int e = 0;
        for (; e + 4 <= cnt; e += 4) {
            body(__builtin_amdgcn_readlane(sReg, e));
            body(__builtin_amdgcn_readlane(sReg, e + 1));
            body(__builtin_amdgcn_readlane(sReg, e + 2));
            body(__builtin_amdgcn_readlane(sReg, e + 3));
        }
        for (; e < cnt; e++) body(__builtin_amdgcn_readlane(sReg, e));
    }

    const float inv = 1.0f / (s + 1e-16f);
    if (MODE == 2) {
        float2 av = __half22float2(acc2);
        ax = av.x; ay = av.y;
    }
    float vx = ax * inv + bias[cl * CH];
    float vy = (CH == 2) ? (ay * inv + bias[cl * CH + 1]) : 0.0f;

    if (MODE == 1) {  // ELU -> bf16
        vx = vx > 0.0f ? vx : expm1f(vx);
        ((u16*)out)[(size_t)node * TOT + cl] = f2bf(vx);
    } else if (MODE == 2) {  // gate -> bf16
        float2 wg = *(const float2*)&Wg[cl * 2];
        float part = vx * wg.x + vy * wg.y;
#pragma unroll
        for (int off = 32; off > 0; off >>= 1) part += __shfl_xor(part, off);
        int d = dist[node];
        float hop = (d <= MAXH) ? (float)d : 0.0f;
        float g = 1.0f / (1.0f + __expf(-(part + hop * Wg[128] + bg[0])));
        ushort2 wv;
        wv.x = f2bf(vx * g);
        wv.y = f2bf(vy * g);
        *(ushort2*)&((u16*)out)[(size_t)node * TOT + cl * 2] = wv;
    } else if (MODE == 3) {  // log_softmax -> fp32
        float v = (lane < NL) ? vx : -INFINITY;
        float mm = v;
#pragma unroll
        for (int off = 32; off > 0; off >>= 1) mm = fmaxf(mm, __shfl_xor(mm, off));
        float ex = (lane < NL) ? __expf(v - mm) : 0.0f;
        float ss = ex;
#pragma unroll
        for (int off = 32; off > 0; off >>= 1) ss += __shfl_xor(ss, off);
        float ls = logf(ss);
        if (lane < NL) ((float*)out)[(size_t)node * TOT + cl] = v - mm - ls;
    }
}

static inline int nblk(long long t, int b) { return (int)((t + b - 1) / b); }

extern "C" void kernel_launch(void* const* d_in, const int* in_sizes, int n_in,
                              void* d_out, int out_size, void* d_ws, size_t ws_size,
                              hipStream_t stream) {
    const float* x = (const float*)d_in[0];
    const int* eidx = (const int*)d_in[1];
    const int* seed_mask = (const int*)d_in[2];
    const float* W1 = (const float*)d_in[3];
    const float* a1s = (const float*)d_in[4];
    const float* a1d = (const float*)d_in[5];
    const float* b1 = (const float*)d_in[6];
    const float* W2 = (const float*)d_in[7];
    const float* a2s = (const float*)d_in[8];
    const float* a2d = (const float*)d_in[9];
    const float* b2 = (const float*)d_in[10];
    const float* W3 = (const float*)d_in[11];
    const float* a3s = (const float*)d_in[12];
    const float* a3d = (const float*)d_in[13];
    const float* b3 = (const float*)d_in[14];
    const float* Wg = (const float*)d_in[15];
    const float* bg = (const float*)d_in[16];

    const int n = in_sizes[0] / 128;        // 100000
    const long long E = in_sizes[1] / 2;    // 1600000
    const int E4 = (int)(E / 4);
    const int4* src4 = (const int4*)eidx;
    const int4* dst4 = (const int4*)(eidx + E);
    const int BINS = (n + NS - 1) >> NSB;   // 196 <= 256
    const int NW = (n + 31) / 32;

    char* ws = (char*)d_ws;
    size_t off = 0;
    auto alloc = [&](size_t bytes) -> void* {
        void* p = ws + off;
        off = (off + bytes + 255) & ~(size_t)255;
        return p;
    };
    int* dist    = (int*)alloc((size_t)n * 4);
    u32* rbits   = (u32*)alloc((size_t)NW * 4);
    u8* nbr      = (u8*)alloc((size_t)n);
    int* rowptr  = (int*)alloc((size_t)(n + 1) * 4);
    int* bincnt  = (int*)alloc(256 * 4);
    int* binbase = (int*)alloc(257 * 4);
    int* bincur  = (int*)alloc(256 * 4);
    int* csr_src = (int*)alloc((size_t)E * 4);
    float* als   = (float*)alloc((size_t)n * 8 * 4);
    float* ald   = (float*)alloc((size_t)n * 8 * 4);
    __half* hbuf = (__half*)alloc((size_t)n * 128 * 2);  // GEMM out (h), fp16
    u16* abuf    = (u16*)alloc((size_t)n * 128 * 2);     // GAT out (next GEMM A), bf16
    int* pairs   = (int*)abuf;  // alias: pairs only live during CSR build
    float* out = (float*)d_out;

    const int BS = 256;

    // ---- CSR build: binned counting sort ----
    hipMemsetAsync(bincnt, 0, 256 * 4, stream);
    k_bfs_init<<<nblk(n, BS), BS, 0, stream>>>(seed_mask, dist, n);
    k_rbits_init<<<nblk(NW, BS), BS, 0, stream>>>(seed_mask, rbits, NW, n);
    k_bincount<<<nblk(E4, BS), BS, 0, stream>>>(dst4, bincnt, E4);
    k_binscan<<<1, 256, 0, stream>>>(bincnt, binbase, bincur, rowptr, BINS, (int)E, n);
    k_binscatter<<<nblk(E4, BS), BS, 0, stream>>>(src4, dst4, bincur, pairs, E4, BINS);
    k_binsort<<<BINS, 256, 0, stream>>>(pairs, binbase, rowptr, csr_src, n);

    // ---- BFS hierarchy via CSR (bitset reached) ----
    for (int h = 1; h <= MAXH; h++) {
        k_bfs_scan<<<nblk(n, BS), BS, 0, stream>>>(rowptr, csr_src, rbits, nbr, n);
        k_bfs_node<<<nblk(n, BS), BS, 0, stream>>>(rbits, dist, nbr, h, n);
    }

    const int mblocks = (n + 15) / 16;
    const int gmf = (mblocks + 15) / 16;   // 4 waves x MBW=4 m-blocks per block

    // ---- Layer 1: aug(132) -> 8x8, ELU fused (MFMA, x converted to bf16 in LDS) ----
    k_gemm_mfma1<136, 4>
        <<<gmf, 256, 0, stream>>>(x, W1, a1s, a1d, dist, hbuf, als, ald, n);
    k_gat<8, 8, 1, 1, u16><<<nblk(n, 4), 256, 0, stream>>>(
        rowptr, csr_src, hbuf, als, ald, b1, nullptr, nullptr, nullptr, abuf, n);

    // ---- Layer 2: 64 -> 8x16, gate fused (MFMA GEMM, bf16 A) ----
    k_gemm_mfma<64, 128, 9, 8, 16, 72, 4>
        <<<gmf, 256, 0, stream>>>(abuf, W2, a2s, a2d, hbuf, als, ald, n);
    k_gat<8, 16, 2, 2, u16><<<nblk(n, 4), 256, 0, stream>>>(
        rowptr, csr_src, hbuf, als, ald, b2, dist, Wg, bg, abuf, n);

    // ---- Layer 3: 128 -> 1x40, log_softmax fused (MFMA GEMM, bf16 A) ----
    k_gemm_mfma<128, 40, 4, 1, 40, 136, 4>
        <<<gmf, 256, 0, stream>>>(abuf, W3, a3s, a3d, hbuf, als, ald, n);
    k_gat<1, 40, 1, 3, float><<<nblk(n, 4), 256, 0, stream>>>(
        rowptr, csr_src, hbuf, als, ald, b3, nullptr, nullptr, nullptr, out, n);
}